// Round 13
// baseline (461.529 us; speedup 1.0000x reference)
//
#include <hip/hip_runtime.h>
#include <hip/hip_bf16.h>

#define NN 50000
#define NE 800000
#define IND 64
#define DIM 128
#define KUPD 256
#define NB_SCAN 196  // ceil(NN/256)
#define NTILE 3125   // NN/16
#define W12S 36864   // per-step wt12 elems: 128*160 (half0) + 128*128 (half1)

typedef __attribute__((ext_vector_type(8))) short bf16x8;
typedef __attribute__((ext_vector_type(4))) short bf16x4;
typedef __attribute__((ext_vector_type(4))) float f32x4;
typedef __attribute__((ext_vector_type(2))) float f32x2;

static __device__ __forceinline__ short f2bf(float f) {
  union { __hip_bfloat16 b; short s; } u;
  u.b = __float2bfloat16(f);
  return u.s;
}
static __device__ __forceinline__ float bf2f(unsigned short u) {
  union { float f; unsigned int i; } x; x.i = ((unsigned int)u) << 16; return x.f;
}
static __device__ __forceinline__ float fexp2(float x) {
  float r; asm("v_exp_f32 %0, %1" : "=v"(r) : "v"(x)); return r;
}
static __device__ __forceinline__ float frcp(float x) {
  float r; asm("v_rcp_f32 %0, %1" : "=v"(r) : "v"(x)); return r;
}
// sum across the 16-lane quarter via DPP row rotates (row = 16 lanes on CDNA)
static __device__ __forceinline__ float qsum16(float x) {
  x += __int_as_float(__builtin_amdgcn_mov_dpp(__float_as_int(x), 0x128, 0xf, 0xf, false));
  x += __int_as_float(__builtin_amdgcn_mov_dpp(__float_as_int(x), 0x124, 0xf, 0xf, false));
  x += __int_as_float(__builtin_amdgcn_mov_dpp(__float_as_int(x), 0x122, 0xf, 0xf, false));
  x += __int_as_float(__builtin_amdgcn_mov_dpp(__float_as_int(x), 0x121, 0xf, 0xf, false));
  return x;
}

// ---------------- embed: hb = bf16(x @ W + b) ----------------
__global__ __launch_bounds__(256) void embed_kernel(
    const float* __restrict__ x, const float* __restrict__ w,
    const float* __restrict__ b, short* __restrict__ hb) {
  __shared__ float ws[IND * DIM];
  __shared__ float xs[8 * IND];
  const int t = threadIdx.x;
  for (int i = t * 4; i < IND * DIM; i += 1024)
    *(float4*)(ws + i) = *(const float4*)(w + i);
  {
    int i = t * 4;
    if (i < 8 * IND)
      *(float4*)(xs + i) = *(const float4*)(x + (size_t)blockIdx.x * (8 * IND) + i);
  }
  __syncthreads();
  const int d = t & 127, g = t >> 7;
  const float bd = b[d];
  for (int nnod = g; nnod < 8; nnod += 2) {
    float acc = bd;
#pragma unroll
    for (int k = 0; k < IND; ++k) acc += xs[nnod * IND + k] * ws[k * DIM + d];
    const size_t n = (size_t)blockIdx.x * 8 + nnod;
    hb[n * DIM + d] = f2bf(acc);
  }
}

// ---------------- degree counts ----------------
__global__ __launch_bounds__(256) void counts_kernel(const int* __restrict__ ei,
                                                     int* __restrict__ cnt) {
  int e = blockIdx.x * 256 + threadIdx.x;
  if (e < NE) atomicAdd(&cnt[ei[NE + e]], 1);
}

// ---------------- fused: per-block sums + degree histogram ----------------
__global__ __launch_bounds__(256) void bsum_dhist_kernel(const int* __restrict__ cnt,
                                                         int* __restrict__ bsum,
                                                         int* __restrict__ dhist) {
  __shared__ int lh[64];
  __shared__ int wsum[4];
  int t = threadIdx.x, idx = blockIdx.x * 256 + t;
  if (t < 64) lh[t] = 0;
  __syncthreads();
  int c = (idx < NN) ? cnt[idx] : 0;
  int s = c;
#pragma unroll
  for (int m = 1; m < 64; m <<= 1) s += __shfl_xor(s, m, 64);
  if ((t & 63) == 0) wsum[t >> 6] = s;
  if (idx < NN) {
    int d = c > 63 ? 63 : c;
    atomicAdd(&lh[63 - d], 1);
  }
  __syncthreads();
  if (t == 0) bsum[blockIdx.x] = wsum[0] + wsum[1] + wsum[2] + wsum[3];
  if (t < 64 && lh[t] > 0) atomicAdd(&dhist[t], lh[t]);
}

// ---------------- fused: block-offset scan + degree-bin scan ----------------
__global__ __launch_bounds__(256) void bscan_dscan_kernel(const int* __restrict__ bsum,
                                                          int* __restrict__ boff,
                                                          const int* __restrict__ dhist,
                                                          int* __restrict__ dcur) {
  __shared__ int sh[256];
  int t = threadIdx.x;
  int v = (t < NB_SCAN) ? bsum[t] : 0;
  sh[t] = v;
  __syncthreads();
  for (int d = 1; d < 256; d <<= 1) {
    int u = (t >= d) ? sh[t - d] : 0;
    __syncthreads();
    sh[t] += u;
    __syncthreads();
  }
  if (t < NB_SCAN) boff[t] = sh[t] - v;  // exclusive
  if (t < 64) {
    int dv = dhist[t];
    int ds = dv;
    for (int d = 1; d < 64; d <<= 1) {
      int u = __shfl_up(ds, d, 64);
      if (t >= d) ds += u;
    }
    dcur[t] = ds - dv;  // exclusive
  }
}

// ---------------- fused: final scan + rden + pos4 + degree-order ----------------
__global__ __launch_bounds__(256) void final_scan_kernel(
    const int* __restrict__ cnt, const int* __restrict__ boff,
    int* __restrict__ dcur, const float* __restrict__ pos,
    int* __restrict__ off, int* __restrict__ cursor, float* __restrict__ rden,
    int* __restrict__ nodeOrd, float4* __restrict__ pos4g) {
  __shared__ int sh[256];
  __shared__ int lh[64];
  __shared__ int lbase[64];
  int b = blockIdx.x, t = threadIdx.x;
  int idx = b * 256 + t;
  bool act = (idx < NN);
  int c = act ? cnt[idx] : 0;
  if (t < 64) lh[t] = 0;
  sh[t] = c;
  __syncthreads();
  for (int d = 1; d < 256; d <<= 1) {
    int u = (t >= d) ? sh[t - d] : 0;
    __syncthreads();
    sh[t] += u;
    __syncthreads();
  }
  int bin = 63 - (c > 63 ? 63 : c);
  int lrank = 0;
  if (act) {
    int e = boff[b] + sh[t] - c;
    off[idx] = e;
    cursor[idx] = e;
    rden[idx] = 1.0f / fmaxf((float)c, 1.0f);
    pos4g[idx] = make_float4(pos[3 * idx], pos[3 * idx + 1], pos[3 * idx + 2], 0.f);
    lrank = atomicAdd(&lh[bin], 1);
  }
  __syncthreads();
  if (t < 64) lbase[t] = (lh[t] > 0) ? atomicAdd(&dcur[t], lh[t]) : 0;
  __syncthreads();
  if (act) nodeOrd[lbase[bin] + lrank] = idx;
  if (b == 0 && t == 0) off[NN] = NE;
}

// ---------------- scatter edges into CSR buckets ----------------
__global__ __launch_bounds__(256) void scatter_kernel(const int* __restrict__ ei,
                                                      int* __restrict__ cursor,
                                                      int* __restrict__ rowOf) {
  int e = blockIdx.x * 256 + threadIdx.x;
  if (e < NE) {
    int c = ei[NE + e];
    int p = atomicAdd(&cursor[c], 1);
    rowOf[p] = ei[e];
  }
}

// ---------------- fused weight transposes ----------------
// wt12 per step: half0 [128 outs][160] = [W1 ; W3 ; 0] (K-extended), half1 [128][128] = W2
__global__ __launch_bounds__(256) void wt_all_kernel(const float* __restrict__ wm,
                                                     const float* __restrict__ wu,
                                                     short* __restrict__ wt12,
                                                     short* __restrict__ wtu) {
  int i = blockIdx.x * 256 + threadIdx.x;
  if (i < 3 * W12S) {
    int s = i / W12S, r = i % W12S;
    float val;
    if (r < 128 * 160) {
      int o = r / 160, k = r % 160;
      if (k < 128)      val = wm[((size_t)s * 259 + k) * DIM + o];
      else if (k < 131) val = wm[((size_t)s * 259 + 256 + (k - 128)) * DIM + o];
      else              val = 0.0f;
    } else {
      int r2 = r - 128 * 160;
      int o = r2 >> 7, k = r2 & 127;
      val = wm[((size_t)s * 259 + 128 + k) * DIM + o];
    }
    wt12[i] = f2bf(val);
  } else {
    int j = i - 3 * W12S;
    if (j < 3 * DIM * KUPD) {
      int k = j % KUPD, d = (j / KUPD) % DIM, s = j / (KUPD * DIM);
      wtu[j] = f2bf(wu[((size_t)s * KUPD + k) * DIM + d]);
    }
  }
}

// ---------------- standalone P13/P2 GEMM (step 0 only) ----------------
// P12b[n][o]     = (h@W1 + pos@W3)[n][o]   (half0, K=160)
// P12b[n][128+o] = (h@W2)[n][o]            (half1, K=128)
__global__ __launch_bounds__(512) void p12_kernel(const short* __restrict__ hb,
                                                  const short* __restrict__ wt12_s,
                                                  const float4* __restrict__ pos4g,
                                                  short* __restrict__ P12b) {
  __shared__ short wlds[128 * 164 + 128 * 132];  // 75.8 KB -> 2 blocks/CU
  short* l0 = wlds;
  short* l1 = wlds + 128 * 164;
  const int t = threadIdx.x;
  const int wid = t >> 6, lane = t & 63;
  const int m = lane & 15, kg = lane >> 4;
  for (int i = t * 8; i < 128 * 160; i += 512 * 8) {
    int r = i / 160, c = i % 160;
    *(bf16x8*)(&l0[r * 164 + c]) = *(const bf16x8*)(wt12_s + i);
  }
  for (int i = t * 8; i < 128 * 128; i += 512 * 8) {
    int r = i >> 7, c = i & 127;
    *(bf16x8*)(&l1[r * 132 + c]) = *(const bf16x8*)(wt12_s + 128 * 160 + i);
  }
  __syncthreads();
  const int wgid = blockIdx.x * 8 + wid;
#pragma unroll
  for (int rep = 0; rep < 2; ++rep) {
    int tid = wgid + rep * 2048;
    if (tid >= NTILE) break;
    int nbase = tid * 16;
    const short* hrow = hb + (size_t)(nbase + m) * DIM;
    bf16x8 bfrag[5];
#pragma unroll
    for (int cc = 0; cc < 4; ++cc)
      bfrag[cc] = *(const bf16x8*)(hrow + cc * 32 + kg * 8);
    {
      bf16x8 b4 = (bf16x8)0;
      if (kg == 0) {
        float4 pp = pos4g[nbase + m];
        b4[0] = f2bf(pp.x); b4[1] = f2bf(pp.y); b4[2] = f2bf(pp.z);
      }
      bfrag[4] = b4;
    }
    // half0: K=160 (h ++ pos)
    {
      f32x4 acc[8];
#pragma unroll
      for (int i = 0; i < 8; ++i) acc[i] = (f32x4)0.0f;
#pragma unroll
      for (int cc = 0; cc < 5; ++cc) {
#pragma unroll
        for (int tl = 0; tl < 8; ++tl) {
          bf16x8 afrag = *(const bf16x8*)(&l0[(tl * 16 + m) * 164 + cc * 32 + kg * 8]);
          acc[tl] = __builtin_amdgcn_mfma_f32_16x16x32_bf16(afrag, bfrag[cc], acc[tl], 0, 0, 0);
        }
      }
#pragma unroll
      for (int tl = 0; tl < 8; ++tl) {
        bf16x4 p;
#pragma unroll
        for (int j = 0; j < 4; ++j) p[j] = f2bf(acc[tl][j]);
        *(bf16x4*)(P12b + (size_t)(nbase + m) * 256 + tl * 16 + kg * 4) = p;
      }
    }
    // half1: K=128
    {
      f32x4 acc[8];
#pragma unroll
      for (int i = 0; i < 8; ++i) acc[i] = (f32x4)0.0f;
#pragma unroll
      for (int cc = 0; cc < 4; ++cc) {
#pragma unroll
        for (int tl = 0; tl < 8; ++tl) {
          bf16x8 afrag = *(const bf16x8*)(&l1[(tl * 16 + m) * 132 + cc * 32 + kg * 8]);
          acc[tl] = __builtin_amdgcn_mfma_f32_16x16x32_bf16(afrag, bfrag[cc], acc[tl], 0, 0, 0);
        }
      }
#pragma unroll
      for (int tl = 0; tl < 8; ++tl) {
        bf16x4 p;
#pragma unroll
        for (int j = 0; j < 4; ++j) p[j] = f2bf(acc[tl][j]);
        *(bf16x4*)(P12b + (size_t)(nbase + m) * 256 + DIM + tl * 16 + kg * 4) = p;
      }
    }
  }
}

// ---------------- message + aggregate ----------------
// v = P13[row] + pb[n], pb = P2[n] - pos[n]@W3 + bias. No per-edge pos work.
__global__ __launch_bounds__(256) void msg_agg_kernel(
    const short* __restrict__ P12b,
    const float4* __restrict__ pos4g,
    const int* __restrict__ rowOf, const int* __restrict__ off,
    const int* __restrict__ nodeOrd, const float* __restrict__ rden,
    const float* __restrict__ wmsg_s,  // msg_w + s*259*128 (f32)
    const float* __restrict__ bias_s, short* __restrict__ aggb) {
  const int t = threadIdx.x;
  const int wid = t >> 6, lane = t & 63;
  const int n = nodeOrd[blockIdx.x * 4 + wid];
  const int q = lane >> 4;
  const int d0 = (lane & 15) * 8;
  f32x2 pbv[4];
  {
    const float4 pc = pos4g[n];
    const float* w30p = wmsg_s + 256 * DIM + d0;
    const float* w31p = wmsg_s + 257 * DIM + d0;
    const float* w32p = wmsg_s + 258 * DIM + d0;
    bf16x8 p2v = *(const bf16x8*)(P12b + (size_t)n * 256 + DIM + d0);
#pragma unroll
    for (int p = 0; p < 4; ++p) {
      f32x2 w0 = *(const f32x2*)(w30p + 2 * p);
      f32x2 w1 = *(const f32x2*)(w31p + 2 * p);
      f32x2 w2 = *(const f32x2*)(w32p + 2 * p);
      f32x2 bb = *(const f32x2*)(bias_s + d0 + 2 * p);
      pbv[p].x = bf2f((unsigned short)p2v[2 * p]) + bb.x
                 - (pc.x * w0.x + pc.y * w1.x + pc.z * w2.x);
      pbv[p].y = bf2f((unsigned short)p2v[2 * p + 1]) + bb.y
                 - (pc.x * w0.y + pc.y * w1.y + pc.z * w2.y);
    }
  }
  const int start = off[n], end = off[n + 1];
  f32x2 av[4];
#pragma unroll
  for (int p = 0; p < 4; ++p) av[p] = (f32x2)0.0f;
  float bacc = 0.f;
  const f32x2 gc1 = (f32x2)(-0.102951604f);
  const f32x2 gc0 = (f32x2)(-2.30234934f);
  const f32x2 onev = (f32x2)1.0f;
  if (start < end) {
    const int last = end - 1;
    int ia = start + q; if (ia > last) ia = last;
    int ra = rowOf[ia];
    bf16x8 p1a = *(const bf16x8*)(P12b + (size_t)ra * 256 + d0);
    int ib = start + 4 + q; if (ib > last) ib = last;
    int rb = rowOf[ib];
    bf16x8 p1b = *(const bf16x8*)(P12b + (size_t)rb * 256 + d0);
#pragma unroll 2
    for (int jg = start; jg < end; jg += 4) {
      int ic = jg + 8 + q; if (ic > last) ic = last;
      int rc = rowOf[ic];
      bf16x8 p1c = *(const bf16x8*)(P12b + (size_t)rc * 256 + d0);
      f32x2 g[4];
      f32x2 s1v = (f32x2)0.0f, s2v = (f32x2)0.0f;
#pragma unroll
      for (int p = 0; p < 4; ++p) {
        unsigned int u = ((const unsigned int*)&p1a)[p];
        f32x2 v;
        v.x = __uint_as_float(u << 16);
        v.y = __uint_as_float(u & 0xffff0000u);
        v = v + pbv[p];
        f32x2 u2 = v * v;
        f32x2 wv = __builtin_elementwise_fma(u2, gc1, gc0);
        f32x2 zv = v * wv;
        f32x2 tv;
        tv.x = fexp2(zv.x);
        tv.y = fexp2(zv.y);
        tv = tv + onev;
        f32x2 rv;
        rv.x = frcp(tv.x);
        rv.y = frcp(tv.y);
        f32x2 gg = v * rv;
        g[p] = gg;
        s1v = s1v + gg;
        s2v = __builtin_elementwise_fma(gg, gg, s2v);
      }
      float s1 = s1v.x + s1v.y;
      float s2 = s2v.x + s2v.y;
      s1 = qsum16(s1);
      s2 = qsum16(s2);
      float mean = s1 * (1.0f / 128.0f);
      float tvv = fmaf(mean, -mean, 1e-5f);
      float var = fmaf(s2, 1.0f / 128.0f, tvv);
      float rstd = rsqrtf(var);
      float rs = (jg + q < end) ? rstd : 0.0f;
      bacc = fmaf(mean, rs, bacc);
      f32x2 rsv = (f32x2)rs;
#pragma unroll
      for (int p = 0; p < 4; ++p) av[p] = __builtin_elementwise_fma(g[p], rsv, av[p]);
      p1a = p1b;
      p1b = p1c;
    }
  }
  const float rd = rden[n];
  float out[8];
#pragma unroll
  for (int p = 0; p < 4; ++p) {
    out[2 * p] = av[p].x - bacc;
    out[2 * p + 1] = av[p].y - bacc;
  }
  bf16x8 ob;
#pragma unroll
  for (int k = 0; k < 8; ++k) {
    out[k] += __shfl_xor(out[k], 16, 64);
    out[k] += __shfl_xor(out[k], 32, 64);
    ob[k] = f2bf(out[k] * rd);
  }
  if (q == 0)
    *(bf16x8*)(aggb + (size_t)n * DIM + d0) = ob;
}

// ---------------- fused update + next-step P13/P2 ----------------
template <int FINAL>
__global__ __launch_bounds__(512) void updp12_kernel(
    const short* hb, const short* __restrict__ aggb,
    const short* __restrict__ wtu_s,   // [128][256]
    const short* __restrict__ wt12_n,  // next step, half0 [128][160] + half1 [128][128]
    const float4* __restrict__ pos4g,
    const float* __restrict__ bias, float* __restrict__ h, short* hbo,
    short* __restrict__ P12b) {
  __shared__ short wlds[128 * 164 + 128 * 132];  // 75.8 KB; phase1 views [128][264]
  const int t = threadIdx.x;
  const int wid = t >> 6, lane = t & 63;
  const int m = lane & 15, kg = lane >> 4;
  for (int i = t * 8; i < DIM * 256; i += 512 * 8) {
    int r = i >> 8, c = i & 255;
    *(bf16x8*)(&wlds[r * 264 + c]) = *(const bf16x8*)(wtu_s + i);
  }
  __syncthreads();
  const int wgid = blockIdx.x * 8 + wid;
#pragma unroll
  for (int rep = 0; rep < 2; ++rep) {
    int tid = wgid + rep * 2048;
    if (tid >= NTILE) break;
    int nbase = tid * 16;
    const int nA = nbase + m;
    const short* hrow = hb + (size_t)nA * DIM;
    const short* arow = aggb + (size_t)nA * DIM;

    f32x4 acc[8];
#pragma unroll
    for (int i = 0; i < 8; ++i) acc[i] = (f32x4)0.0f;
#pragma unroll
    for (int cc = 0; cc < 8; ++cc) {
      bf16x8 a = (cc < 4) ? *(const bf16x8*)(hrow + cc * 32 + kg * 8)
                          : *(const bf16x8*)(arow + (cc - 4) * 32 + kg * 8);
#pragma unroll
      for (int tl = 0; tl < 8; ++tl) {
        bf16x8 bfr = *(const bf16x8*)(&wlds[(tl * 16 + m) * 264 + cc * 32 + kg * 8]);
        acc[tl] = __builtin_amdgcn_mfma_f32_16x16x32_bf16(a, bfr, acc[tl], 0, 0, 0);
      }
    }

    float s1[4] = {0.f, 0.f, 0.f, 0.f}, s2[4] = {0.f, 0.f, 0.f, 0.f};
#pragma unroll
    for (int tl = 0; tl < 8; ++tl) {
      float bd = bias[tl * 16 + m];
#pragma unroll
      for (int j = 0; j < 4; ++j) {
        float xv = acc[tl][j] + bd;
        acc[tl][j] = xv;
        s1[j] += xv;
        s2[j] = fmaf(xv, xv, s2[j]);
      }
    }
#pragma unroll
    for (int mask = 1; mask < 16; mask <<= 1) {
#pragma unroll
      for (int j = 0; j < 4; ++j) {
        s1[j] += __shfl_xor(s1[j], mask, 64);
        s2[j] += __shfl_xor(s2[j], mask, 64);
      }
    }
#pragma unroll
    for (int j = 0; j < 4; ++j) {
      float mean = s1[j] * (1.0f / 128.0f);
      float var = s2[j] * (1.0f / 128.0f) - mean * mean;
      float rstd = rsqrtf(var + 1e-5f);
      int nw = nbase + kg * 4 + j;
#pragma unroll
      for (int tl = 0; tl < 8; ++tl) {
        int d = tl * 16 + m;
        float res = bf2f((unsigned short)hb[(size_t)nw * DIM + d]);
        float hv = res + (acc[tl][j] - mean) * rstd;
        if (FINAL) h[(size_t)nw * DIM + d] = hv;
        else       hbo[(size_t)nw * DIM + d] = f2bf(hv);
      }
    }
  }
  if (FINAL) return;

  // ---- phase 2: next-step P13/P2 from freshly written hbo ----
  __syncthreads();
  short* l0 = wlds;
  short* l1 = wlds + 128 * 164;
  for (int i = t * 8; i < 128 * 160; i += 512 * 8) {
    int r = i / 160, c = i % 160;
    *(bf16x8*)(&l0[r * 164 + c]) = *(const bf16x8*)(wt12_n + i);
  }
  for (int i = t * 8; i < 128 * 128; i += 512 * 8) {
    int r = i >> 7, c = i & 127;
    *(bf16x8*)(&l1[r * 132 + c]) = *(const bf16x8*)(wt12_n + 128 * 160 + i);
  }
  __syncthreads();
#pragma unroll
  for (int rep = 0; rep < 2; ++rep) {
    int tid = wgid + rep * 2048;
    if (tid >= NTILE) break;
    int nbase = tid * 16;
    const short* hrow = hbo + (size_t)(nbase + m) * DIM;
    bf16x8 bfrag[5];
#pragma unroll
    for (int cc = 0; cc < 4; ++cc)
      bfrag[cc] = *(const bf16x8*)(hrow + cc * 32 + kg * 8);
    {
      bf16x8 b4 = (bf16x8)0;
      if (kg == 0) {
        float4 pp = pos4g[nbase + m];
        b4[0] = f2bf(pp.x); b4[1] = f2bf(pp.y); b4[2] = f2bf(pp.z);
      }
      bfrag[4] = b4;
    }
    {
      f32x4 acc[8];
#pragma unroll
      for (int i = 0; i < 8; ++i) acc[i] = (f32x4)0.0f;
#pragma unroll
      for (int cc = 0; cc < 5; ++cc) {
#pragma unroll
        for (int tl = 0; tl < 8; ++tl) {
          bf16x8 afrag = *(const bf16x8*)(&l0[(tl * 16 + m) * 164 + cc * 32 + kg * 8]);
          acc[tl] = __builtin_amdgcn_mfma_f32_16x16x32_bf16(afrag, bfrag[cc], acc[tl], 0, 0, 0);
        }
      }
#pragma unroll
      for (int tl = 0; tl < 8; ++tl) {
        bf16x4 p;
#pragma unroll
        for (int j = 0; j < 4; ++j) p[j] = f2bf(acc[tl][j]);
        *(bf16x4*)(P12b + (size_t)(nbase + m) * 256 + tl * 16 + kg * 4) = p;
      }
    }
    {
      f32x4 acc[8];
#pragma unroll
      for (int i = 0; i < 8; ++i) acc[i] = (f32x4)0.0f;
#pragma unroll
      for (int cc = 0; cc < 4; ++cc) {
#pragma unroll
        for (int tl = 0; tl < 8; ++tl) {
          bf16x8 afrag = *(const bf16x8*)(&l1[(tl * 16 + m) * 132 + cc * 32 + kg * 8]);
          acc[tl] = __builtin_amdgcn_mfma_f32_16x16x32_bf16(afrag, bfrag[cc], acc[tl], 0, 0, 0);
        }
      }
#pragma unroll
      for (int tl = 0; tl < 8; ++tl) {
        bf16x4 p;
#pragma unroll
        for (int j = 0; j < 4; ++j) p[j] = f2bf(acc[tl][j]);
        *(bf16x4*)(P12b + (size_t)(nbase + m) * 256 + DIM + tl * 16 + kg * 4) = p;
      }
    }
  }
}

extern "C" void kernel_launch(void* const* d_in, const int* in_sizes, int n_in,
                              void* d_out, int out_size, void* d_ws, size_t ws_size,
                              hipStream_t stream) {
  const float* x       = (const float*)d_in[0];
  const float* pos     = (const float*)d_in[1];
  const int* ei        = (const int*)d_in[2];
  const float* embed_w = (const float*)d_in[3];
  const float* embed_b = (const float*)d_in[4];
  const float* msg_w   = (const float*)d_in[5];
  const float* msg_b   = (const float*)d_in[6];
  const float* upd_w   = (const float*)d_in[7];
  const float* upd_b   = (const float*)d_in[8];
  float* h = (float*)d_out;

  char* ws = (char*)d_ws;
  size_t off_b = 0;
  short* hb     = (short*)(ws + off_b);  off_b += (size_t)NN * DIM * 2;
  short* P12b   = (short*)(ws + off_b);  off_b += (size_t)NN * 256 * 2;
  short* aggb   = (short*)(ws + off_b);  off_b += (size_t)NN * DIM * 2;
  float* rden   = (float*)(ws + off_b);  off_b += (size_t)NN * 4;
  int*   cnt    = (int*)(ws + off_b);    off_b += (size_t)NN * 4;
  int*   offs   = (int*)(ws + off_b);    off_b += (size_t)(NN + 16) * 4;
  int*   cursor = (int*)(ws + off_b);    off_b += (size_t)NN * 4;
  int*   rowOf  = (int*)(ws + off_b);    off_b += (size_t)(NE + 16) * 4;
  int*   bsum   = (int*)(ws + off_b);    off_b += (size_t)256 * 4;
  int*   boff   = (int*)(ws + off_b);    off_b += (size_t)256 * 4;
  int*   dhist  = (int*)(ws + off_b);    off_b += (size_t)64 * 4;
  int*   dcur   = (int*)(ws + off_b);    off_b += (size_t)64 * 4;
  int*   nodeOrd= (int*)(ws + off_b);    off_b += (size_t)NN * 4;
  float4* pos4g = (float4*)(ws + off_b); off_b += (size_t)NN * 16;
  short* wt12   = (short*)(ws + off_b);  off_b += (size_t)3 * W12S * 2;
  short* wtu    = (short*)(ws + off_b);  off_b += (size_t)3 * DIM * KUPD * 2;

  hipMemsetAsync(cnt, 0, (size_t)NN * 4, stream);
  hipMemsetAsync(dhist, 0, 64 * 4, stream);
  counts_kernel<<<(NE + 255) / 256, 256, 0, stream>>>(ei, cnt);
  bsum_dhist_kernel<<<NB_SCAN, 256, 0, stream>>>(cnt, bsum, dhist);
  bscan_dscan_kernel<<<1, 256, 0, stream>>>(bsum, boff, dhist, dcur);
  final_scan_kernel<<<NB_SCAN, 256, 0, stream>>>(cnt, boff, dcur, pos,
                                                 offs, cursor, rden, nodeOrd, pos4g);
  scatter_kernel<<<(NE + 255) / 256, 256, 0, stream>>>(ei, cursor, rowOf);
  wt_all_kernel<<<(3 * W12S + 3 * DIM * KUPD + 255) / 256, 256, 0, stream>>>(
      msg_w, upd_w, wt12, wtu);
  embed_kernel<<<NN / 8, 256, 0, stream>>>(x, embed_w, embed_b, hb);
  p12_kernel<<<256, 512, 0, stream>>>(hb, wt12, pos4g, P12b);

  for (int s = 0; s < 3; ++s) {
    msg_agg_kernel<<<NN / 4, 256, 0, stream>>>(P12b, pos4g, rowOf, offs, nodeOrd, rden,
                                               msg_w + (size_t)s * 259 * DIM,
                                               msg_b + (size_t)s * DIM, aggb);
    if (s < 2)
      updp12_kernel<0><<<256, 512, 0, stream>>>(
          hb, aggb, wtu + (size_t)s * DIM * KUPD,
          wt12 + (size_t)(s + 1) * W12S, pos4g,
          upd_b + (size_t)s * DIM, h, hb, P12b);
    else
      updp12_kernel<1><<<256, 512, 0, stream>>>(
          hb, aggb, wtu + (size_t)s * DIM * KUPD,
          wt12, pos4g,
          upd_b + (size_t)s * DIM, h, hb, P12b);
  }
}

// Round 14
// 393.778 us; speedup vs baseline: 1.1721x; 1.1721x over previous
//
#include <hip/hip_runtime.h>
#include <hip/hip_bf16.h>

#define NN 50000
#define NE 800000
#define IND 64
#define DIM 128
#define KUPD 256
#define NB_SCAN 196  // ceil(NN/256)
#define NTILE 3125   // NN/16

typedef __attribute__((ext_vector_type(8))) short bf16x8;
typedef __attribute__((ext_vector_type(4))) short bf16x4;
typedef __attribute__((ext_vector_type(4))) float f32x4;
typedef __attribute__((ext_vector_type(2))) float f32x2;

static __device__ __forceinline__ short f2bf(float f) {
  union { __hip_bfloat16 b; short s; } u;
  u.b = __float2bfloat16(f);
  return u.s;
}
static __device__ __forceinline__ float bf2f(unsigned short u) {
  union { float f; unsigned int i; } x; x.i = ((unsigned int)u) << 16; return x.f;
}
static __device__ __forceinline__ float fexp2(float x) {
  float r; asm("v_exp_f32 %0, %1" : "=v"(r) : "v"(x)); return r;
}
static __device__ __forceinline__ float frcp(float x) {
  float r; asm("v_rcp_f32 %0, %1" : "=v"(r) : "v"(x)); return r;
}
// sum across the 16-lane quarter via DPP row rotates (row = 16 lanes on CDNA)
static __device__ __forceinline__ float qsum16(float x) {
  x += __int_as_float(__builtin_amdgcn_mov_dpp(__float_as_int(x), 0x128, 0xf, 0xf, false));
  x += __int_as_float(__builtin_amdgcn_mov_dpp(__float_as_int(x), 0x124, 0xf, 0xf, false));
  x += __int_as_float(__builtin_amdgcn_mov_dpp(__float_as_int(x), 0x122, 0xf, 0xf, false));
  x += __int_as_float(__builtin_amdgcn_mov_dpp(__float_as_int(x), 0x121, 0xf, 0xf, false));
  return x;
}

// ---------------- embed: hb = bf16(x @ W + b) ----------------
__global__ __launch_bounds__(256) void embed_kernel(
    const float* __restrict__ x, const float* __restrict__ w,
    const float* __restrict__ b, short* __restrict__ hb) {
  __shared__ float ws[IND * DIM];
  __shared__ float xs[8 * IND];
  const int t = threadIdx.x;
  for (int i = t * 4; i < IND * DIM; i += 1024)
    *(float4*)(ws + i) = *(const float4*)(w + i);
  {
    int i = t * 4;
    if (i < 8 * IND)
      *(float4*)(xs + i) = *(const float4*)(x + (size_t)blockIdx.x * (8 * IND) + i);
  }
  __syncthreads();
  const int d = t & 127, g = t >> 7;
  const float bd = b[d];
  for (int nnod = g; nnod < 8; nnod += 2) {
    float acc = bd;
#pragma unroll
    for (int k = 0; k < IND; ++k) acc += xs[nnod * IND + k] * ws[k * DIM + d];
    const size_t n = (size_t)blockIdx.x * 8 + nnod;
    hb[n * DIM + d] = f2bf(acc);
  }
}

// ---------------- degree counts ----------------
__global__ __launch_bounds__(256) void counts_kernel(const int* __restrict__ ei,
                                                     int* __restrict__ cnt) {
  int e = blockIdx.x * 256 + threadIdx.x;
  if (e < NE) atomicAdd(&cnt[ei[NE + e]], 1);
}

// ---------------- fused: per-block sums + degree histogram ----------------
__global__ __launch_bounds__(256) void bsum_dhist_kernel(const int* __restrict__ cnt,
                                                         int* __restrict__ bsum,
                                                         int* __restrict__ dhist) {
  __shared__ int lh[64];
  __shared__ int wsum[4];
  int t = threadIdx.x, idx = blockIdx.x * 256 + t;
  if (t < 64) lh[t] = 0;
  __syncthreads();
  int c = (idx < NN) ? cnt[idx] : 0;
  int s = c;
#pragma unroll
  for (int m = 1; m < 64; m <<= 1) s += __shfl_xor(s, m, 64);
  if ((t & 63) == 0) wsum[t >> 6] = s;
  if (idx < NN) {
    int d = c > 63 ? 63 : c;
    atomicAdd(&lh[63 - d], 1);
  }
  __syncthreads();
  if (t == 0) bsum[blockIdx.x] = wsum[0] + wsum[1] + wsum[2] + wsum[3];
  if (t < 64 && lh[t] > 0) atomicAdd(&dhist[t], lh[t]);
}

// ---------------- fused: block-offset scan + degree-bin scan ----------------
__global__ __launch_bounds__(256) void bscan_dscan_kernel(const int* __restrict__ bsum,
                                                          int* __restrict__ boff,
                                                          const int* __restrict__ dhist,
                                                          int* __restrict__ dcur) {
  __shared__ int sh[256];
  int t = threadIdx.x;
  int v = (t < NB_SCAN) ? bsum[t] : 0;
  sh[t] = v;
  __syncthreads();
  for (int d = 1; d < 256; d <<= 1) {
    int u = (t >= d) ? sh[t - d] : 0;
    __syncthreads();
    sh[t] += u;
    __syncthreads();
  }
  if (t < NB_SCAN) boff[t] = sh[t] - v;  // exclusive
  if (t < 64) {
    int dv = dhist[t];
    int ds = dv;
    for (int d = 1; d < 64; d <<= 1) {
      int u = __shfl_up(ds, d, 64);
      if (t >= d) ds += u;
    }
    dcur[t] = ds - dv;  // exclusive
  }
}

// ---------------- fused: final scan + rden + pos4 + degree-order ----------------
__global__ __launch_bounds__(256) void final_scan_kernel(
    const int* __restrict__ cnt, const int* __restrict__ boff,
    int* __restrict__ dcur, const float* __restrict__ pos,
    int* __restrict__ off, int* __restrict__ cursor, float* __restrict__ rden,
    int* __restrict__ nodeOrd, float4* __restrict__ pos4g) {
  __shared__ int sh[256];
  __shared__ int lh[64];
  __shared__ int lbase[64];
  int b = blockIdx.x, t = threadIdx.x;
  int idx = b * 256 + t;
  bool act = (idx < NN);
  int c = act ? cnt[idx] : 0;
  if (t < 64) lh[t] = 0;
  sh[t] = c;
  __syncthreads();
  for (int d = 1; d < 256; d <<= 1) {
    int u = (t >= d) ? sh[t - d] : 0;
    __syncthreads();
    sh[t] += u;
    __syncthreads();
  }
  int bin = 63 - (c > 63 ? 63 : c);
  int lrank = 0;
  if (act) {
    int e = boff[b] + sh[t] - c;
    off[idx] = e;
    cursor[idx] = e;
    rden[idx] = 1.0f / fmaxf((float)c, 1.0f);
    pos4g[idx] = make_float4(pos[3 * idx], pos[3 * idx + 1], pos[3 * idx + 2], 0.f);
    lrank = atomicAdd(&lh[bin], 1);
  }
  __syncthreads();
  if (t < 64) lbase[t] = (lh[t] > 0) ? atomicAdd(&dcur[t], lh[t]) : 0;
  __syncthreads();
  if (act) nodeOrd[lbase[bin] + lrank] = idx;
  if (b == 0 && t == 0) off[NN] = NE;
}

// ---------------- scatter edges into CSR buckets ----------------
__global__ __launch_bounds__(256) void scatter_kernel(const int* __restrict__ ei,
                                                      int* __restrict__ cursor,
                                                      int* __restrict__ rowOf) {
  int e = blockIdx.x * 256 + threadIdx.x;
  if (e < NE) {
    int c = ei[NE + e];
    int p = atomicAdd(&cursor[c], 1);
    rowOf[p] = ei[e];
  }
}

// ---------------- fused weight transposes (R12 layout) ----------------
__global__ __launch_bounds__(256) void wt_all_kernel(const float* __restrict__ wm,
                                                     const float* __restrict__ wu,
                                                     short* __restrict__ wt12,
                                                     short* __restrict__ wtu) {
  int i = blockIdx.x * 256 + threadIdx.x;
  if (i < 3 * 256 * DIM) {
    int k = i % DIM, o = (i / DIM) % 256, s = i / (DIM * 256);
    int krow = (o < DIM) ? k : (DIM + k);
    int d = o & (DIM - 1);
    wt12[i] = f2bf(wm[((size_t)s * 259 + krow) * DIM + d]);
  } else {
    int j = i - 3 * 256 * DIM;
    if (j < 3 * DIM * KUPD) {
      int k = j % KUPD, d = (j / KUPD) % DIM, s = j / (KUPD * DIM);
      wtu[j] = f2bf(wu[((size_t)s * KUPD + k) * DIM + d]);
    }
  }
}

// ---------------- standalone P13/P2 GEMM (step 0): K=128 + epilogue pos@W3 fold --
__global__ __launch_bounds__(512) void p12_kernel(const short* __restrict__ hb,
                                                  const short* __restrict__ wt12_s,  // [256][128]
                                                  const float4* __restrict__ pos4g,
                                                  const float* __restrict__ w3,  // [3][128]
                                                  short* __restrict__ P12b) {
  __shared__ short wlds[256 * 132];  // 67.6 KB
  __shared__ float w3lds[384];       // 1.5 KB
  const int t = threadIdx.x;
  const int wid = t >> 6, lane = t & 63;
  const int m = lane & 15, kg = lane >> 4;
  for (int i = t * 8; i < 256 * DIM; i += 512 * 8) {
    int r = i >> 7, c = i & 127;
    *(bf16x8*)(&wlds[r * 132 + c]) = *(const bf16x8*)(wt12_s + i);
  }
  if (t < 384) w3lds[t] = w3[t];
  __syncthreads();
  const int wgid = blockIdx.x * 8 + wid;
#pragma unroll
  for (int rep = 0; rep < 2; ++rep) {
    int tid = wgid + rep * 2048;
    if (tid >= NTILE) break;
    int nbase = tid * 16;
    const short* hrow = hb + (size_t)(nbase + m) * DIM;
    const float4 pp = pos4g[nbase + m];
    bf16x8 bfrag[4];
#pragma unroll
    for (int cc = 0; cc < 4; ++cc)
      bfrag[cc] = *(const bf16x8*)(hrow + cc * 32 + kg * 8);
#pragma unroll
    for (int half = 0; half < 2; ++half) {
      f32x4 acc[8];
#pragma unroll
      for (int i = 0; i < 8; ++i) acc[i] = (f32x4)0.0f;
#pragma unroll
      for (int cc = 0; cc < 4; ++cc) {
#pragma unroll
        for (int tl = 0; tl < 8; ++tl) {
          bf16x8 afrag = *(const bf16x8*)(&wlds[(half * DIM + tl * 16 + m) * 132 + cc * 32 + kg * 8]);
          acc[tl] = __builtin_amdgcn_mfma_f32_16x16x32_bf16(afrag, bfrag[cc], acc[tl], 0, 0, 0);
        }
      }
#pragma unroll
      for (int tl = 0; tl < 8; ++tl) {
        bf16x4 p;
#pragma unroll
        for (int j = 0; j < 4; ++j) {
          float val = acc[tl][j];
          if (half == 0) {
            int o = tl * 16 + kg * 4 + j;
            val += pp.x * w3lds[o] + pp.y * w3lds[128 + o] + pp.z * w3lds[256 + o];
          }
          p[j] = f2bf(val);
        }
        *(bf16x4*)(P12b + (size_t)(nbase + m) * 256 + half * DIM + tl * 16 + kg * 4) = p;
      }
    }
  }
}

// ---------------- message + aggregate (R13-proven: pure inner loop) ----------------
__global__ __launch_bounds__(256) void msg_agg_kernel(
    const short* __restrict__ P12b,
    const float4* __restrict__ pos4g,
    const int* __restrict__ rowOf, const int* __restrict__ off,
    const int* __restrict__ nodeOrd, const float* __restrict__ rden,
    const float* __restrict__ wmsg_s,  // msg_w + s*259*128 (f32)
    const float* __restrict__ bias_s, short* __restrict__ aggb) {
  const int t = threadIdx.x;
  const int wid = t >> 6, lane = t & 63;
  const int n = nodeOrd[blockIdx.x * 4 + wid];
  const int q = lane >> 4;
  const int d0 = (lane & 15) * 8;
  f32x2 pbv[4];
  {
    const float4 pc = pos4g[n];
    const float* w30p = wmsg_s + 256 * DIM + d0;
    const float* w31p = wmsg_s + 257 * DIM + d0;
    const float* w32p = wmsg_s + 258 * DIM + d0;
    bf16x8 p2v = *(const bf16x8*)(P12b + (size_t)n * 256 + DIM + d0);
#pragma unroll
    for (int p = 0; p < 4; ++p) {
      f32x2 w0 = *(const f32x2*)(w30p + 2 * p);
      f32x2 w1 = *(const f32x2*)(w31p + 2 * p);
      f32x2 w2 = *(const f32x2*)(w32p + 2 * p);
      f32x2 bb = *(const f32x2*)(bias_s + d0 + 2 * p);
      pbv[p].x = bf2f((unsigned short)p2v[2 * p]) + bb.x
                 - (pc.x * w0.x + pc.y * w1.x + pc.z * w2.x);
      pbv[p].y = bf2f((unsigned short)p2v[2 * p + 1]) + bb.y
                 - (pc.x * w0.y + pc.y * w1.y + pc.z * w2.y);
    }
  }
  const int start = off[n], end = off[n + 1];
  f32x2 av[4];
#pragma unroll
  for (int p = 0; p < 4; ++p) av[p] = (f32x2)0.0f;
  float bacc = 0.f;
  const f32x2 gc1 = (f32x2)(-0.102951604f);
  const f32x2 gc0 = (f32x2)(-2.30234934f);
  const f32x2 onev = (f32x2)1.0f;
  if (start < end) {
    const int last = end - 1;
    int ia = start + q; if (ia > last) ia = last;
    int ra = rowOf[ia];
    bf16x8 p1a = *(const bf16x8*)(P12b + (size_t)ra * 256 + d0);
    int ib = start + 4 + q; if (ib > last) ib = last;
    int rb = rowOf[ib];
    bf16x8 p1b = *(const bf16x8*)(P12b + (size_t)rb * 256 + d0);
#pragma unroll 2
    for (int jg = start; jg < end; jg += 4) {
      int ic = jg + 8 + q; if (ic > last) ic = last;
      int rc = rowOf[ic];
      bf16x8 p1c = *(const bf16x8*)(P12b + (size_t)rc * 256 + d0);
      f32x2 g[4];
      f32x2 s1v = (f32x2)0.0f, s2v = (f32x2)0.0f;
#pragma unroll
      for (int p = 0; p < 4; ++p) {
        unsigned int u = ((const unsigned int*)&p1a)[p];
        f32x2 v;
        v.x = __uint_as_float(u << 16);
        v.y = __uint_as_float(u & 0xffff0000u);
        v = v + pbv[p];
        f32x2 u2 = v * v;
        f32x2 wv = __builtin_elementwise_fma(u2, gc1, gc0);
        f32x2 zv = v * wv;
        f32x2 tv;
        tv.x = fexp2(zv.x);
        tv.y = fexp2(zv.y);
        tv = tv + onev;
        f32x2 rv;
        rv.x = frcp(tv.x);
        rv.y = frcp(tv.y);
        f32x2 gg = v * rv;
        g[p] = gg;
        s1v = s1v + gg;
        s2v = __builtin_elementwise_fma(gg, gg, s2v);
      }
      float s1 = s1v.x + s1v.y;
      float s2 = s2v.x + s2v.y;
      s1 = qsum16(s1);
      s2 = qsum16(s2);
      float mean = s1 * (1.0f / 128.0f);
      float tvv = fmaf(mean, -mean, 1e-5f);
      float var = fmaf(s2, 1.0f / 128.0f, tvv);
      float rstd = rsqrtf(var);
      float rs = (jg + q < end) ? rstd : 0.0f;
      bacc = fmaf(mean, rs, bacc);
      f32x2 rsv = (f32x2)rs;
#pragma unroll
      for (int p = 0; p < 4; ++p) av[p] = __builtin_elementwise_fma(g[p], rsv, av[p]);
      p1a = p1b;
      p1b = p1c;
    }
  }
  const float rd = rden[n];
  float out[8];
#pragma unroll
  for (int p = 0; p < 4; ++p) {
    out[2 * p] = av[p].x - bacc;
    out[2 * p + 1] = av[p].y - bacc;
  }
  bf16x8 ob;
#pragma unroll
  for (int k = 0; k < 8; ++k) {
    out[k] += __shfl_xor(out[k], 16, 64);
    out[k] += __shfl_xor(out[k], 32, 64);
    ob[k] = f2bf(out[k] * rd);
  }
  if (q == 0)
    *(bf16x8*)(aggb + (size_t)n * DIM + d0) = ob;
}

// ---------------- fused update + next-step P13/P2 (R12 structure + epilogue fold) --
template <int FINAL>
__global__ __launch_bounds__(512) void updp12_kernel(
    const short* hb, const short* __restrict__ aggb,
    const short* __restrict__ wtu_s,   // [128][256]
    const short* __restrict__ wt12_n,  // [256][128] for next step
    const float4* __restrict__ pos4g,
    const float* __restrict__ w3_n,    // [3][128] next step
    const float* __restrict__ bias, float* __restrict__ h, short* hbo,
    short* __restrict__ P12b) {
  __shared__ short wlds[33792];  // 67.6 KB; viewed [128][264] then [256][132]
  __shared__ float w3lds[384];   // 1.5 KB
  const int t = threadIdx.x;
  const int wid = t >> 6, lane = t & 63;
  const int m = lane & 15, kg = lane >> 4;
  for (int i = t * 8; i < DIM * 256; i += 512 * 8) {
    int r = i >> 8, c = i & 255;
    *(bf16x8*)(&wlds[r * 264 + c]) = *(const bf16x8*)(wtu_s + i);
  }
  if (!FINAL && t < 384) w3lds[t] = w3_n[t];
  __syncthreads();
  const int wgid = blockIdx.x * 8 + wid;
#pragma unroll
  for (int rep = 0; rep < 2; ++rep) {
    int tid = wgid + rep * 2048;
    if (tid >= NTILE) break;
    int nbase = tid * 16;
    const int nA = nbase + m;
    const short* hrow = hb + (size_t)nA * DIM;
    const short* arow = aggb + (size_t)nA * DIM;

    f32x4 acc[8];
#pragma unroll
    for (int i = 0; i < 8; ++i) acc[i] = (f32x4)0.0f;
#pragma unroll
    for (int cc = 0; cc < 8; ++cc) {
      bf16x8 a = (cc < 4) ? *(const bf16x8*)(hrow + cc * 32 + kg * 8)
                          : *(const bf16x8*)(arow + (cc - 4) * 32 + kg * 8);
#pragma unroll
      for (int tl = 0; tl < 8; ++tl) {
        bf16x8 bfr = *(const bf16x8*)(&wlds[(tl * 16 + m) * 264 + cc * 32 + kg * 8]);
        acc[tl] = __builtin_amdgcn_mfma_f32_16x16x32_bf16(a, bfr, acc[tl], 0, 0, 0);
      }
    }

    float s1[4] = {0.f, 0.f, 0.f, 0.f}, s2[4] = {0.f, 0.f, 0.f, 0.f};
#pragma unroll
    for (int tl = 0; tl < 8; ++tl) {
      float bd = bias[tl * 16 + m];
#pragma unroll
      for (int j = 0; j < 4; ++j) {
        float xv = acc[tl][j] + bd;
        acc[tl][j] = xv;
        s1[j] += xv;
        s2[j] = fmaf(xv, xv, s2[j]);
      }
    }
#pragma unroll
    for (int mask = 1; mask < 16; mask <<= 1) {
#pragma unroll
      for (int j = 0; j < 4; ++j) {
        s1[j] += __shfl_xor(s1[j], mask, 64);
        s2[j] += __shfl_xor(s2[j], mask, 64);
      }
    }
#pragma unroll
    for (int j = 0; j < 4; ++j) {
      float mean = s1[j] * (1.0f / 128.0f);
      float var = s2[j] * (1.0f / 128.0f) - mean * mean;
      float rstd = rsqrtf(var + 1e-5f);
      int nw = nbase + kg * 4 + j;
#pragma unroll
      for (int tl = 0; tl < 8; ++tl) {
        int d = tl * 16 + m;
        float res = bf2f((unsigned short)hb[(size_t)nw * DIM + d]);
        float hv = res + (acc[tl][j] - mean) * rstd;
        if (FINAL) h[(size_t)nw * DIM + d] = hv;
        else       hbo[(size_t)nw * DIM + d] = f2bf(hv);
      }
    }
  }
  if (FINAL) return;

  // ---- phase 2: next-step P13/P2 from freshly written hbo ----
  __syncthreads();
  for (int i = t * 8; i < 256 * DIM; i += 512 * 8) {
    int r = i >> 7, c = i & 127;
    *(bf16x8*)(&wlds[r * 132 + c]) = *(const bf16x8*)(wt12_n + i);
  }
  __syncthreads();
#pragma unroll
  for (int rep = 0; rep < 2; ++rep) {
    int tid = wgid + rep * 2048;
    if (tid >= NTILE) break;
    int nbase = tid * 16;
    const short* hrow = hbo + (size_t)(nbase + m) * DIM;
    const float4 pp = pos4g[nbase + m];
    bf16x8 bfrag[4];
#pragma unroll
    for (int cc = 0; cc < 4; ++cc)
      bfrag[cc] = *(const bf16x8*)(hrow + cc * 32 + kg * 8);
#pragma unroll
    for (int half = 0; half < 2; ++half) {
      f32x4 acc[8];
#pragma unroll
      for (int i = 0; i < 8; ++i) acc[i] = (f32x4)0.0f;
#pragma unroll
      for (int cc = 0; cc < 4; ++cc) {
#pragma unroll
        for (int tl = 0; tl < 8; ++tl) {
          bf16x8 afrag = *(const bf16x8*)(&wlds[(half * DIM + tl * 16 + m) * 132 + cc * 32 + kg * 8]);
          acc[tl] = __builtin_amdgcn_mfma_f32_16x16x32_bf16(afrag, bfrag[cc], acc[tl], 0, 0, 0);
        }
      }
#pragma unroll
      for (int tl = 0; tl < 8; ++tl) {
        bf16x4 p;
#pragma unroll
        for (int j = 0; j < 4; ++j) {
          float val = acc[tl][j];
          if (half == 0) {
            int o = tl * 16 + kg * 4 + j;
            val += pp.x * w3lds[o] + pp.y * w3lds[128 + o] + pp.z * w3lds[256 + o];
          }
          p[j] = f2bf(val);
        }
        *(bf16x4*)(P12b + (size_t)(nbase + m) * 256 + half * DIM + tl * 16 + kg * 4) = p;
      }
    }
  }
}

extern "C" void kernel_launch(void* const* d_in, const int* in_sizes, int n_in,
                              void* d_out, int out_size, void* d_ws, size_t ws_size,
                              hipStream_t stream) {
  const float* x       = (const float*)d_in[0];
  const float* pos     = (const float*)d_in[1];
  const int* ei        = (const int*)d_in[2];
  const float* embed_w = (const float*)d_in[3];
  const float* embed_b = (const float*)d_in[4];
  const float* msg_w   = (const float*)d_in[5];
  const float* msg_b   = (const float*)d_in[6];
  const float* upd_w   = (const float*)d_in[7];
  const float* upd_b   = (const float*)d_in[8];
  float* h = (float*)d_out;

  char* ws = (char*)d_ws;
  size_t off_b = 0;
  short* hb     = (short*)(ws + off_b);  off_b += (size_t)NN * DIM * 2;
  short* P12b   = (short*)(ws + off_b);  off_b += (size_t)NN * 256 * 2;
  short* aggb   = (short*)(ws + off_b);  off_b += (size_t)NN * DIM * 2;
  float* rden   = (float*)(ws + off_b);  off_b += (size_t)NN * 4;
  int*   cnt    = (int*)(ws + off_b);    off_b += (size_t)NN * 4;
  int*   offs   = (int*)(ws + off_b);    off_b += (size_t)(NN + 16) * 4;
  int*   cursor = (int*)(ws + off_b);    off_b += (size_t)NN * 4;
  int*   rowOf  = (int*)(ws + off_b);    off_b += (size_t)(NE + 16) * 4;
  int*   bsum   = (int*)(ws + off_b);    off_b += (size_t)256 * 4;
  int*   boff   = (int*)(ws + off_b);    off_b += (size_t)256 * 4;
  int*   dhist  = (int*)(ws + off_b);    off_b += (size_t)64 * 4;
  int*   dcur   = (int*)(ws + off_b);    off_b += (size_t)64 * 4;
  int*   nodeOrd= (int*)(ws + off_b);    off_b += (size_t)NN * 4;
  float4* pos4g = (float4*)(ws + off_b); off_b += (size_t)NN * 16;
  short* wt12   = (short*)(ws + off_b);  off_b += (size_t)3 * 256 * DIM * 2;
  short* wtu    = (short*)(ws + off_b);  off_b += (size_t)3 * DIM * KUPD * 2;

  hipMemsetAsync(cnt, 0, (size_t)NN * 4, stream);
  hipMemsetAsync(dhist, 0, 64 * 4, stream);
  counts_kernel<<<(NE + 255) / 256, 256, 0, stream>>>(ei, cnt);
  bsum_dhist_kernel<<<NB_SCAN, 256, 0, stream>>>(cnt, bsum, dhist);
  bscan_dscan_kernel<<<1, 256, 0, stream>>>(bsum, boff, dhist, dcur);
  final_scan_kernel<<<NB_SCAN, 256, 0, stream>>>(cnt, boff, dcur, pos,
                                                 offs, cursor, rden, nodeOrd, pos4g);
  scatter_kernel<<<(NE + 255) / 256, 256, 0, stream>>>(ei, cursor, rowOf);
  wt_all_kernel<<<(3 * 256 * DIM + 3 * DIM * KUPD + 255) / 256, 256, 0, stream>>>(
      msg_w, upd_w, wt12, wtu);
  embed_kernel<<<NN / 8, 256, 0, stream>>>(x, embed_w, embed_b, hb);
  p12_kernel<<<256, 512, 0, stream>>>(hb, wt12, pos4g, msg_w + 256 * DIM, P12b);

  for (int s = 0; s < 3; ++s) {
    msg_agg_kernel<<<NN / 4, 256, 0, stream>>>(P12b, pos4g, rowOf, offs, nodeOrd, rden,
                                               msg_w + (size_t)s * 259 * DIM,
                                               msg_b + (size_t)s * DIM, aggb);
    if (s < 2)
      updp12_kernel<0><<<256, 512, 0, stream>>>(
          hb, aggb, wtu + (size_t)s * DIM * KUPD,
          wt12 + (size_t)(s + 1) * 256 * DIM, pos4g,
          msg_w + (size_t)(s + 1) * 259 * DIM + 256 * DIM,
          upd_b + (size_t)s * DIM, h, hb, P12b);
    else
      updp12_kernel<1><<<256, 512, 0, stream>>>(
          hb, aggb, wtu + (size_t)s * DIM * KUPD,
          wt12, pos4g, msg_w,
          upd_b + (size_t)s * DIM, h, hb, P12b);
  }
}

// Round 15
// 382.272 us; speedup vs baseline: 1.2073x; 1.0301x over previous
//
#include <hip/hip_runtime.h>
#include <hip/hip_bf16.h>

#define NN 50000
#define NE 800000
#define IND 64
#define DIM 128
#define KUPD 256
#define NB_SCAN 196  // ceil(NN/256)
#define NTILE 3125   // NN/16
#define NB_EMB 6250  // NN/8
#define NB_CNT 3125  // ceil(NE/256)
#define NB_WT 768    // (3*256*128 + 3*128*256)/256
#define NB_SCT 1563  // ceil(NE/512)

typedef __attribute__((ext_vector_type(8))) short bf16x8;
typedef __attribute__((ext_vector_type(4))) short bf16x4;
typedef __attribute__((ext_vector_type(4))) float f32x4;
typedef __attribute__((ext_vector_type(2))) float f32x2;

static __device__ __forceinline__ short f2bf(float f) {
  union { __hip_bfloat16 b; short s; } u;
  u.b = __float2bfloat16(f);
  return u.s;
}
static __device__ __forceinline__ float bf2f(unsigned short u) {
  union { float f; unsigned int i; } x; x.i = ((unsigned int)u) << 16; return x.f;
}
static __device__ __forceinline__ float fexp2(float x) {
  float r; asm("v_exp_f32 %0, %1" : "=v"(r) : "v"(x)); return r;
}
static __device__ __forceinline__ float frcp(float x) {
  float r; asm("v_rcp_f32 %0, %1" : "=v"(r) : "v"(x)); return r;
}
// sum across the 16-lane quarter via DPP row rotates (row = 16 lanes on CDNA)
static __device__ __forceinline__ float qsum16(float x) {
  x += __int_as_float(__builtin_amdgcn_mov_dpp(__float_as_int(x), 0x128, 0xf, 0xf, false));
  x += __int_as_float(__builtin_amdgcn_mov_dpp(__float_as_int(x), 0x124, 0xf, 0xf, false));
  x += __int_as_float(__builtin_amdgcn_mov_dpp(__float_as_int(x), 0x122, 0xf, 0xf, false));
  x += __int_as_float(__builtin_amdgcn_mov_dpp(__float_as_int(x), 0x121, 0xf, 0xf, false));
  return x;
}

// ---------------- fused setup: embed | counts | weight transposes ----------------
__global__ __launch_bounds__(256) void setup_kernel(
    const float* __restrict__ x, const float* __restrict__ ew,
    const float* __restrict__ eb, short* __restrict__ hb,
    const int* __restrict__ ei, int* __restrict__ cnt,
    const float* __restrict__ wm, const float* __restrict__ wu,
    short* __restrict__ wt12, short* __restrict__ wtu) {
  __shared__ float ws[IND * DIM];   // 32 KB
  __shared__ float xs[8 * IND];     // 2 KB
  const int bid = blockIdx.x;
  const int t = threadIdx.x;
  if (bid < NB_EMB) {
    // ---- embed: 8 nodes per block ----
    for (int i = t * 4; i < IND * DIM; i += 1024)
      *(float4*)(ws + i) = *(const float4*)(ew + i);
    {
      int i = t * 4;
      if (i < 8 * IND)
        *(float4*)(xs + i) = *(const float4*)(x + (size_t)bid * (8 * IND) + i);
    }
    __syncthreads();
    const int d = t & 127, g = t >> 7;
    const float bd = eb[d];
    for (int nnod = g; nnod < 8; nnod += 2) {
      float acc = bd;
#pragma unroll
      for (int k = 0; k < IND; ++k) acc += xs[nnod * IND + k] * ws[k * DIM + d];
      const size_t n = (size_t)bid * 8 + nnod;
      hb[n * DIM + d] = f2bf(acc);
    }
  } else if (bid < NB_EMB + NB_CNT) {
    // ---- degree counts ----
    int e = (bid - NB_EMB) * 256 + t;
    if (e < NE) atomicAdd(&cnt[ei[NE + e]], 1);
  } else {
    // ---- weight transposes ----
    int i = (bid - NB_EMB - NB_CNT) * 256 + t;
    if (i < 3 * 256 * DIM) {
      int k = i % DIM, o = (i / DIM) % 256, s = i / (DIM * 256);
      int krow = (o < DIM) ? k : (DIM + k);
      int d = o & (DIM - 1);
      wt12[i] = f2bf(wm[((size_t)s * 259 + krow) * DIM + d]);
    } else {
      int j = i - 3 * 256 * DIM;
      if (j < 3 * DIM * KUPD) {
        int k = j % KUPD, d = (j / KUPD) % DIM, s = j / (KUPD * DIM);
        wtu[j] = f2bf(wu[((size_t)s * KUPD + k) * DIM + d]);
      }
    }
  }
}

// ---------------- fused: per-block sums + degree histogram ----------------
__global__ __launch_bounds__(256) void bsum_dhist_kernel(const int* __restrict__ cnt,
                                                         int* __restrict__ bsum,
                                                         int* __restrict__ dhist) {
  __shared__ int lh[64];
  __shared__ int wsum[4];
  int t = threadIdx.x, idx = blockIdx.x * 256 + t;
  if (t < 64) lh[t] = 0;
  __syncthreads();
  int c = (idx < NN) ? cnt[idx] : 0;
  int s = c;
#pragma unroll
  for (int m = 1; m < 64; m <<= 1) s += __shfl_xor(s, m, 64);
  if ((t & 63) == 0) wsum[t >> 6] = s;
  if (idx < NN) {
    int d = c > 63 ? 63 : c;
    atomicAdd(&lh[63 - d], 1);
  }
  __syncthreads();
  if (t == 0) bsum[blockIdx.x] = wsum[0] + wsum[1] + wsum[2] + wsum[3];
  if (t < 64 && lh[t] > 0) atomicAdd(&dhist[t], lh[t]);
}

// ---------------- fused: block-offset scan + degree-bin scan ----------------
__global__ __launch_bounds__(256) void bscan_dscan_kernel(const int* __restrict__ bsum,
                                                          int* __restrict__ boff,
                                                          const int* __restrict__ dhist,
                                                          int* __restrict__ dcur) {
  __shared__ int sh[256];
  int t = threadIdx.x;
  int v = (t < NB_SCAN) ? bsum[t] : 0;
  sh[t] = v;
  __syncthreads();
  for (int d = 1; d < 256; d <<= 1) {
    int u = (t >= d) ? sh[t - d] : 0;
    __syncthreads();
    sh[t] += u;
    __syncthreads();
  }
  if (t < NB_SCAN) boff[t] = sh[t] - v;  // exclusive
  if (t < 64) {
    int dv = dhist[t];
    int ds = dv;
    for (int d = 1; d < 64; d <<= 1) {
      int u = __shfl_up(ds, d, 64);
      if (t >= d) ds += u;
    }
    dcur[t] = ds - dv;  // exclusive
  }
}

// ---------------- fused: final scan + rden + pos4 + degree-order ----------------
__global__ __launch_bounds__(256) void final_scan_kernel(
    const int* __restrict__ cnt, const int* __restrict__ boff,
    int* __restrict__ dcur, const float* __restrict__ pos,
    int* __restrict__ off, int* __restrict__ cursor, float* __restrict__ rden,
    int* __restrict__ nodeOrd, float4* __restrict__ pos4g) {
  __shared__ int sh[256];
  __shared__ int lh[64];
  __shared__ int lbase[64];
  int b = blockIdx.x, t = threadIdx.x;
  int idx = b * 256 + t;
  bool act = (idx < NN);
  int c = act ? cnt[idx] : 0;
  if (t < 64) lh[t] = 0;
  sh[t] = c;
  __syncthreads();
  for (int d = 1; d < 256; d <<= 1) {
    int u = (t >= d) ? sh[t - d] : 0;
    __syncthreads();
    sh[t] += u;
    __syncthreads();
  }
  int bin = 63 - (c > 63 ? 63 : c);
  int lrank = 0;
  if (act) {
    int e = boff[b] + sh[t] - c;
    off[idx] = e;
    cursor[idx] = e;
    rden[idx] = 1.0f / fmaxf((float)c, 1.0f);
    pos4g[idx] = make_float4(pos[3 * idx], pos[3 * idx + 1], pos[3 * idx + 2], 0.f);
    lrank = atomicAdd(&lh[bin], 1);
  }
  __syncthreads();
  if (t < 64) lbase[t] = (lh[t] > 0) ? atomicAdd(&dcur[t], lh[t]) : 0;
  __syncthreads();
  if (act) nodeOrd[lbase[bin] + lrank] = idx;
  if (b == 0 && t == 0) off[NN] = NE;
}

// ---------------- fused: step-0 P13/P2 GEMM | edge scatter ----------------
__global__ __launch_bounds__(512) void scatter_p12_kernel(
    const short* __restrict__ hb, const short* __restrict__ wt12_s,  // [256][128]
    const float4* __restrict__ pos4g, const float* __restrict__ w3,  // [3][128]
    short* __restrict__ P12b,
    const int* __restrict__ ei, int* __restrict__ cursor, int* __restrict__ rowOf) {
  __shared__ short wlds[256 * 132];  // 67.6 KB
  __shared__ float w3lds[384];       // 1.5 KB
  const int bid = blockIdx.x;
  const int t = threadIdx.x;
  if (bid >= 256) {
    // ---- scatter ----
    int e = (bid - 256) * 512 + t;
    if (e < NE) {
      int c = ei[NE + e];
      int p = atomicAdd(&cursor[c], 1);
      rowOf[p] = ei[e];
    }
    return;
  }
  // ---- p12 ----
  const int wid = t >> 6, lane = t & 63;
  const int m = lane & 15, kg = lane >> 4;
  for (int i = t * 8; i < 256 * DIM; i += 512 * 8) {
    int r = i >> 7, c = i & 127;
    *(bf16x8*)(&wlds[r * 132 + c]) = *(const bf16x8*)(wt12_s + i);
  }
  if (t < 384) w3lds[t] = w3[t];
  __syncthreads();
  const int wgid = bid * 8 + wid;
#pragma unroll
  for (int rep = 0; rep < 2; ++rep) {
    int tid = wgid + rep * 2048;
    if (tid >= NTILE) break;
    int nbase = tid * 16;
    const short* hrow = hb + (size_t)(nbase + m) * DIM;
    const float4 pp = pos4g[nbase + m];
    bf16x8 bfrag[4];
#pragma unroll
    for (int cc = 0; cc < 4; ++cc)
      bfrag[cc] = *(const bf16x8*)(hrow + cc * 32 + kg * 8);
#pragma unroll
    for (int half = 0; half < 2; ++half) {
      f32x4 acc[8];
#pragma unroll
      for (int i = 0; i < 8; ++i) acc[i] = (f32x4)0.0f;
#pragma unroll
      for (int cc = 0; cc < 4; ++cc) {
#pragma unroll
        for (int tl = 0; tl < 8; ++tl) {
          bf16x8 afrag = *(const bf16x8*)(&wlds[(half * DIM + tl * 16 + m) * 132 + cc * 32 + kg * 8]);
          acc[tl] = __builtin_amdgcn_mfma_f32_16x16x32_bf16(afrag, bfrag[cc], acc[tl], 0, 0, 0);
        }
      }
#pragma unroll
      for (int tl = 0; tl < 8; ++tl) {
        bf16x4 p;
#pragma unroll
        for (int j = 0; j < 4; ++j) {
          float val = acc[tl][j];
          if (half == 0) {
            int o = tl * 16 + kg * 4 + j;
            val += pp.x * w3lds[o] + pp.y * w3lds[128 + o] + pp.z * w3lds[256 + o];
          }
          p[j] = f2bf(val);
        }
        *(bf16x4*)(P12b + (size_t)(nbase + m) * 256 + half * DIM + tl * 16 + kg * 4) = p;
      }
    }
  }
}

// ---------------- message + aggregate (R13-proven: pure inner loop) ----------------
__global__ __launch_bounds__(256) void msg_agg_kernel(
    const short* __restrict__ P12b,
    const float4* __restrict__ pos4g,
    const int* __restrict__ rowOf, const int* __restrict__ off,
    const int* __restrict__ nodeOrd, const float* __restrict__ rden,
    const float* __restrict__ wmsg_s,  // msg_w + s*259*128 (f32)
    const float* __restrict__ bias_s, short* __restrict__ aggb) {
  const int t = threadIdx.x;
  const int wid = t >> 6, lane = t & 63;
  const int n = nodeOrd[blockIdx.x * 4 + wid];
  const int q = lane >> 4;
  const int d0 = (lane & 15) * 8;
  f32x2 pbv[4];
  {
    const float4 pc = pos4g[n];
    const float* w30p = wmsg_s + 256 * DIM + d0;
    const float* w31p = wmsg_s + 257 * DIM + d0;
    const float* w32p = wmsg_s + 258 * DIM + d0;
    bf16x8 p2v = *(const bf16x8*)(P12b + (size_t)n * 256 + DIM + d0);
#pragma unroll
    for (int p = 0; p < 4; ++p) {
      f32x2 w0 = *(const f32x2*)(w30p + 2 * p);
      f32x2 w1 = *(const f32x2*)(w31p + 2 * p);
      f32x2 w2 = *(const f32x2*)(w32p + 2 * p);
      f32x2 bb = *(const f32x2*)(bias_s + d0 + 2 * p);
      pbv[p].x = bf2f((unsigned short)p2v[2 * p]) + bb.x
                 - (pc.x * w0.x + pc.y * w1.x + pc.z * w2.x);
      pbv[p].y = bf2f((unsigned short)p2v[2 * p + 1]) + bb.y
                 - (pc.x * w0.y + pc.y * w1.y + pc.z * w2.y);
    }
  }
  const int start = off[n], end = off[n + 1];
  f32x2 av[4];
#pragma unroll
  for (int p = 0; p < 4; ++p) av[p] = (f32x2)0.0f;
  float bacc = 0.f;
  const f32x2 gc1 = (f32x2)(-0.102951604f);
  const f32x2 gc0 = (f32x2)(-2.30234934f);
  const f32x2 onev = (f32x2)1.0f;
  if (start < end) {
    const int last = end - 1;
    int ia = start + q; if (ia > last) ia = last;
    int ra = rowOf[ia];
    bf16x8 p1a = *(const bf16x8*)(P12b + (size_t)ra * 256 + d0);
    int ib = start + 4 + q; if (ib > last) ib = last;
    int rb = rowOf[ib];
    bf16x8 p1b = *(const bf16x8*)(P12b + (size_t)rb * 256 + d0);
#pragma unroll 2
    for (int jg = start; jg < end; jg += 4) {
      int ic = jg + 8 + q; if (ic > last) ic = last;
      int rc = rowOf[ic];
      bf16x8 p1c = *(const bf16x8*)(P12b + (size_t)rc * 256 + d0);
      f32x2 g[4];
      f32x2 s1v = (f32x2)0.0f, s2v = (f32x2)0.0f;
#pragma unroll
      for (int p = 0; p < 4; ++p) {
        unsigned int u = ((const unsigned int*)&p1a)[p];
        f32x2 v;
        v.x = __uint_as_float(u << 16);
        v.y = __uint_as_float(u & 0xffff0000u);
        v = v + pbv[p];
        f32x2 u2 = v * v;
        f32x2 wv = __builtin_elementwise_fma(u2, gc1, gc0);
        f32x2 zv = v * wv;
        f32x2 tv;
        tv.x = fexp2(zv.x);
        tv.y = fexp2(zv.y);
        tv = tv + onev;
        f32x2 rv;
        rv.x = frcp(tv.x);
        rv.y = frcp(tv.y);
        f32x2 gg = v * rv;
        g[p] = gg;
        s1v = s1v + gg;
        s2v = __builtin_elementwise_fma(gg, gg, s2v);
      }
      float s1 = s1v.x + s1v.y;
      float s2 = s2v.x + s2v.y;
      s1 = qsum16(s1);
      s2 = qsum16(s2);
      float mean = s1 * (1.0f / 128.0f);
      float tvv = fmaf(mean, -mean, 1e-5f);
      float var = fmaf(s2, 1.0f / 128.0f, tvv);
      float rstd = rsqrtf(var);
      float rs = (jg + q < end) ? rstd : 0.0f;
      bacc = fmaf(mean, rs, bacc);
      f32x2 rsv = (f32x2)rs;
#pragma unroll
      for (int p = 0; p < 4; ++p) av[p] = __builtin_elementwise_fma(g[p], rsv, av[p]);
      p1a = p1b;
      p1b = p1c;
    }
  }
  const float rd = rden[n];
  float out[8];
#pragma unroll
  for (int p = 0; p < 4; ++p) {
    out[2 * p] = av[p].x - bacc;
    out[2 * p + 1] = av[p].y - bacc;
  }
  bf16x8 ob;
#pragma unroll
  for (int k = 0; k < 8; ++k) {
    out[k] += __shfl_xor(out[k], 16, 64);
    out[k] += __shfl_xor(out[k], 32, 64);
    ob[k] = f2bf(out[k] * rd);
  }
  if (q == 0)
    *(bf16x8*)(aggb + (size_t)n * DIM + d0) = ob;
}

// ---------------- fused update + next-step P13/P2 (R12 structure + epilogue fold) --
template <int FINAL>
__global__ __launch_bounds__(512) void updp12_kernel(
    const short* hb, const short* __restrict__ aggb,
    const short* __restrict__ wtu_s,   // [128][256]
    const short* __restrict__ wt12_n,  // [256][128] for next step
    const float4* __restrict__ pos4g,
    const float* __restrict__ w3_n,    // [3][128] next step
    const float* __restrict__ bias, float* __restrict__ h, short* hbo,
    short* __restrict__ P12b) {
  __shared__ short wlds[33792];  // 67.6 KB; viewed [128][264] then [256][132]
  __shared__ float w3lds[384];   // 1.5 KB
  const int t = threadIdx.x;
  const int wid = t >> 6, lane = t & 63;
  const int m = lane & 15, kg = lane >> 4;
  for (int i = t * 8; i < DIM * 256; i += 512 * 8) {
    int r = i >> 8, c = i & 255;
    *(bf16x8*)(&wlds[r * 264 + c]) = *(const bf16x8*)(wtu_s + i);
  }
  if (!FINAL && t < 384) w3lds[t] = w3_n[t];
  __syncthreads();
  const int wgid = blockIdx.x * 8 + wid;
#pragma unroll
  for (int rep = 0; rep < 2; ++rep) {
    int tid = wgid + rep * 2048;
    if (tid >= NTILE) break;
    int nbase = tid * 16;
    const int nA = nbase + m;
    const short* hrow = hb + (size_t)nA * DIM;
    const short* arow = aggb + (size_t)nA * DIM;

    f32x4 acc[8];
#pragma unroll
    for (int i = 0; i < 8; ++i) acc[i] = (f32x4)0.0f;
#pragma unroll
    for (int cc = 0; cc < 8; ++cc) {
      bf16x8 a = (cc < 4) ? *(const bf16x8*)(hrow + cc * 32 + kg * 8)
                          : *(const bf16x8*)(arow + (cc - 4) * 32 + kg * 8);
#pragma unroll
      for (int tl = 0; tl < 8; ++tl) {
        bf16x8 bfr = *(const bf16x8*)(&wlds[(tl * 16 + m) * 264 + cc * 32 + kg * 8]);
        acc[tl] = __builtin_amdgcn_mfma_f32_16x16x32_bf16(a, bfr, acc[tl], 0, 0, 0);
      }
    }

    float s1[4] = {0.f, 0.f, 0.f, 0.f}, s2[4] = {0.f, 0.f, 0.f, 0.f};
#pragma unroll
    for (int tl = 0; tl < 8; ++tl) {
      float bd = bias[tl * 16 + m];
#pragma unroll
      for (int j = 0; j < 4; ++j) {
        float xv = acc[tl][j] + bd;
        acc[tl][j] = xv;
        s1[j] += xv;
        s2[j] = fmaf(xv, xv, s2[j]);
      }
    }
#pragma unroll
    for (int mask = 1; mask < 16; mask <<= 1) {
#pragma unroll
      for (int j = 0; j < 4; ++j) {
        s1[j] += __shfl_xor(s1[j], mask, 64);
        s2[j] += __shfl_xor(s2[j], mask, 64);
      }
    }
#pragma unroll
    for (int j = 0; j < 4; ++j) {
      float mean = s1[j] * (1.0f / 128.0f);
      float var = s2[j] * (1.0f / 128.0f) - mean * mean;
      float rstd = rsqrtf(var + 1e-5f);
      int nw = nbase + kg * 4 + j;
#pragma unroll
      for (int tl = 0; tl < 8; ++tl) {
        int d = tl * 16 + m;
        float res = bf2f((unsigned short)hb[(size_t)nw * DIM + d]);
        float hv = res + (acc[tl][j] - mean) * rstd;
        if (FINAL) h[(size_t)nw * DIM + d] = hv;
        else       hbo[(size_t)nw * DIM + d] = f2bf(hv);
      }
    }
  }
  if (FINAL) return;

  // ---- phase 2: next-step P13/P2 from freshly written hbo ----
  __syncthreads();
  for (int i = t * 8; i < 256 * DIM; i += 512 * 8) {
    int r = i >> 7, c = i & 127;
    *(bf16x8*)(&wlds[r * 132 + c]) = *(const bf16x8*)(wt12_n + i);
  }
  __syncthreads();
#pragma unroll
  for (int rep = 0; rep < 2; ++rep) {
    int tid = wgid + rep * 2048;
    if (tid >= NTILE) break;
    int nbase = tid * 16;
    const short* hrow = hbo + (size_t)(nbase + m) * DIM;
    const float4 pp = pos4g[nbase + m];
    bf16x8 bfrag[4];
#pragma unroll
    for (int cc = 0; cc < 4; ++cc)
      bfrag[cc] = *(const bf16x8*)(hrow + cc * 32 + kg * 8);
#pragma unroll
    for (int half = 0; half < 2; ++half) {
      f32x4 acc[8];
#pragma unroll
      for (int i = 0; i < 8; ++i) acc[i] = (f32x4)0.0f;
#pragma unroll
      for (int cc = 0; cc < 4; ++cc) {
#pragma unroll
        for (int tl = 0; tl < 8; ++tl) {
          bf16x8 afrag = *(const bf16x8*)(&wlds[(half * DIM + tl * 16 + m) * 132 + cc * 32 + kg * 8]);
          acc[tl] = __builtin_amdgcn_mfma_f32_16x16x32_bf16(afrag, bfrag[cc], acc[tl], 0, 0, 0);
        }
      }
#pragma unroll
      for (int tl = 0; tl < 8; ++tl) {
        bf16x4 p;
#pragma unroll
        for (int j = 0; j < 4; ++j) {
          float val = acc[tl][j];
          if (half == 0) {
            int o = tl * 16 + kg * 4 + j;
            val += pp.x * w3lds[o] + pp.y * w3lds[128 + o] + pp.z * w3lds[256 + o];
          }
          p[j] = f2bf(val);
        }
        *(bf16x4*)(P12b + (size_t)(nbase + m) * 256 + half * DIM + tl * 16 + kg * 4) = p;
      }
    }
  }
}

extern "C" void kernel_launch(void* const* d_in, const int* in_sizes, int n_in,
                              void* d_out, int out_size, void* d_ws, size_t ws_size,
                              hipStream_t stream) {
  const float* x       = (const float*)d_in[0];
  const float* pos     = (const float*)d_in[1];
  const int* ei        = (const int*)d_in[2];
  const float* embed_w = (const float*)d_in[3];
  const float* embed_b = (const float*)d_in[4];
  const float* msg_w   = (const float*)d_in[5];
  const float* msg_b   = (const float*)d_in[6];
  const float* upd_w   = (const float*)d_in[7];
  const float* upd_b   = (const float*)d_in[8];
  float* h = (float*)d_out;

  char* ws = (char*)d_ws;
  size_t off_b = 0;
  short* hb     = (short*)(ws + off_b);  off_b += (size_t)NN * DIM * 2;
  short* P12b   = (short*)(ws + off_b);  off_b += (size_t)NN * 256 * 2;
  short* aggb   = (short*)(ws + off_b);  off_b += (size_t)NN * DIM * 2;
  float* rden   = (float*)(ws + off_b);  off_b += (size_t)NN * 4;
  int*   cnt    = (int*)(ws + off_b);    off_b += (size_t)NN * 4;
  int*   offs   = (int*)(ws + off_b);    off_b += (size_t)(NN + 16) * 4;
  int*   cursor = (int*)(ws + off_b);    off_b += (size_t)NN * 4;
  int*   rowOf  = (int*)(ws + off_b);    off_b += (size_t)(NE + 16) * 4;
  int*   bsum   = (int*)(ws + off_b);    off_b += (size_t)256 * 4;
  int*   boff   = (int*)(ws + off_b);    off_b += (size_t)256 * 4;
  int*   dhist  = (int*)(ws + off_b);    off_b += (size_t)64 * 4;
  int*   dcur   = (int*)(ws + off_b);    off_b += (size_t)64 * 4;
  int*   nodeOrd= (int*)(ws + off_b);    off_b += (size_t)NN * 4;
  float4* pos4g = (float4*)(ws + off_b); off_b += (size_t)NN * 16;
  short* wt12   = (short*)(ws + off_b);  off_b += (size_t)3 * 256 * DIM * 2;
  short* wtu    = (short*)(ws + off_b);  off_b += (size_t)3 * DIM * KUPD * 2;

  hipMemsetAsync(cnt, 0, (size_t)NN * 4, stream);
  hipMemsetAsync(dhist, 0, 64 * 4, stream);
  setup_kernel<<<NB_EMB + NB_CNT + NB_WT, 256, 0, stream>>>(
      x, embed_w, embed_b, hb, ei, cnt, msg_w, upd_w, wt12, wtu);
  bsum_dhist_kernel<<<NB_SCAN, 256, 0, stream>>>(cnt, bsum, dhist);
  bscan_dscan_kernel<<<1, 256, 0, stream>>>(bsum, boff, dhist, dcur);
  final_scan_kernel<<<NB_SCAN, 256, 0, stream>>>(cnt, boff, dcur, pos,
                                                 offs, cursor, rden, nodeOrd, pos4g);
  scatter_p12_kernel<<<256 + NB_SCT, 512, 0, stream>>>(
      hb, wt12, pos4g, msg_w + 256 * DIM, P12b, ei, cursor, rowOf);

  for (int s = 0; s < 3; ++s) {
    msg_agg_kernel<<<NN / 4, 256, 0, stream>>>(P12b, pos4g, rowOf, offs, nodeOrd, rden,
                                               msg_w + (size_t)s * 259 * DIM,
                                               msg_b + (size_t)s * DIM, aggb);
    if (s < 2)
      updp12_kernel<0><<<256, 512, 0, stream>>>(
          hb, aggb, wtu + (size_t)s * DIM * KUPD,
          wt12 + (size_t)(s + 1) * 256 * DIM, pos4g,
          msg_w + (size_t)(s + 1) * 259 * DIM + 256 * DIM,
          upd_b + (size_t)s * DIM, h, hb, P12b);
    else
      updp12_kernel<1><<<256, 512, 0, stream>>>(
          hb, aggb, wtu + (size_t)s * DIM * KUPD,
          wt12, pos4g, msg_w,
          upd_b + (size_t)s * DIM, h, hb, P12b);
  }
}

// Round 16
// 349.136 us; speedup vs baseline: 1.3219x; 1.0949x over previous
//
#include <hip/hip_runtime.h>
#include <hip/hip_bf16.h>

#define NN 50000
#define NE 800000
#define IND 64
#define DIM 128
#define KUPD 256
#define NB_SCAN 196  // ceil(NN/256)
#define NTILE 3125   // NN/16
#define NB_SCT1 3125 // NE/256
#define NB_WT 768

typedef __attribute__((ext_vector_type(8))) short bf16x8;
typedef __attribute__((ext_vector_type(4))) short bf16x4;
typedef __attribute__((ext_vector_type(4))) float f32x4;
typedef __attribute__((ext_vector_type(2))) float f32x2;

static __device__ __forceinline__ short f2bf(float f) {
  union { __hip_bfloat16 b; short s; } u;
  u.b = __float2bfloat16(f);
  return u.s;
}
static __device__ __forceinline__ float bf2f(unsigned short u) {
  union { float f; unsigned int i; } x; x.i = ((unsigned int)u) << 16; return x.f;
}
static __device__ __forceinline__ float fexp2(float x) {
  float r; asm("v_exp_f32 %0, %1" : "=v"(r) : "v"(x)); return r;
}
static __device__ __forceinline__ float frcp(float x) {
  float r; asm("v_rcp_f32 %0, %1" : "=v"(r) : "v"(x)); return r;
}
// sum across the 16-lane quarter via DPP row rotates (row = 16 lanes on CDNA)
static __device__ __forceinline__ float qsum16(float x) {
  x += __int_as_float(__builtin_amdgcn_mov_dpp(__float_as_int(x), 0x128, 0xf, 0xf, false));
  x += __int_as_float(__builtin_amdgcn_mov_dpp(__float_as_int(x), 0x124, 0xf, 0xf, false));
  x += __int_as_float(__builtin_amdgcn_mov_dpp(__float_as_int(x), 0x122, 0xf, 0xf, false));
  x += __int_as_float(__builtin_amdgcn_mov_dpp(__float_as_int(x), 0x121, 0xf, 0xf, false));
  return x;
}

// ---------------- embed: hb = bf16(x @ W + b) ----------------
__global__ __launch_bounds__(256) void embed_kernel(
    const float* __restrict__ x, const float* __restrict__ w,
    const float* __restrict__ b, short* __restrict__ hb) {
  __shared__ float ws[IND * DIM];
  __shared__ float xs[8 * IND];
  const int t = threadIdx.x;
  for (int i = t * 4; i < IND * DIM; i += 1024)
    *(float4*)(ws + i) = *(const float4*)(w + i);
  {
    int i = t * 4;
    if (i < 8 * IND)
      *(float4*)(xs + i) = *(const float4*)(x + (size_t)blockIdx.x * (8 * IND) + i);
  }
  __syncthreads();
  const int d = t & 127, g = t >> 7;
  const float bd = b[d];
  for (int nnod = g; nnod < 8; nnod += 2) {
    float acc = bd;
#pragma unroll
    for (int k = 0; k < IND; ++k) acc += xs[nnod * IND + k] * ws[k * DIM + d];
    const size_t n = (size_t)blockIdx.x * 8 + nnod;
    hb[n * DIM + d] = f2bf(acc);
  }
}

// ---- single-pass edge bucketing (cnt + rowOf2) fused with weight transposes ----
__global__ __launch_bounds__(256) void scatter_wt_kernel(
    const int* __restrict__ ei, int* __restrict__ cnt, int* __restrict__ rowOf2,
    const float* __restrict__ wm, const float* __restrict__ wu,
    short* __restrict__ wt12, short* __restrict__ wtu) {
  const int bid = blockIdx.x, t = threadIdx.x;
  if (bid < NB_SCT1) {
    int e = bid * 256 + t;
    if (e < NE) {
      int c = ei[NE + e];
      int r = atomicAdd(&cnt[c], 1);
      if (r < 64) rowOf2[(size_t)c * 64 + r] = ei[e];
    }
  } else {
    int i = (bid - NB_SCT1) * 256 + t;
    if (i < 3 * 256 * DIM) {
      int k = i % DIM, o = (i / DIM) % 256, s = i / (DIM * 256);
      int krow = (o < DIM) ? k : (DIM + k);
      int d = o & (DIM - 1);
      wt12[i] = f2bf(wm[((size_t)s * 259 + krow) * DIM + d]);
    } else {
      int j = i - 3 * 256 * DIM;
      if (j < 3 * DIM * KUPD) {
        int k = j % KUPD, d = (j / KUPD) % DIM, s = j / (KUPD * DIM);
        wtu[j] = f2bf(wu[((size_t)s * KUPD + k) * DIM + d]);
      }
    }
  }
}

// ---------------- degree histogram (LDS-aggregated) ----------------
__global__ __launch_bounds__(256) void dhist_kernel(const int* __restrict__ cnt,
                                                    int* __restrict__ dhist) {
  __shared__ int lh[64];
  int t = threadIdx.x, n = blockIdx.x * 256 + t;
  if (t < 64) lh[t] = 0;
  __syncthreads();
  if (n < NN) {
    int d = cnt[n]; if (d > 63) d = 63;
    atomicAdd(&lh[63 - d], 1);
  }
  __syncthreads();
  if (t < 64 && lh[t] > 0) atomicAdd(&dhist[t], lh[t]);
}
__global__ __launch_bounds__(64) void dscan_kernel(const int* __restrict__ dhist,
                                                   int* __restrict__ dcur) {
  int t = threadIdx.x;
  int v = dhist[t];
  int s = v;
  for (int d = 1; d < 64; d <<= 1) {
    int u = __shfl_up(s, d, 64);
    if (t >= d) s += u;
  }
  dcur[t] = s - v;  // exclusive
}

// ---------------- order + rden + pos4 ----------------
__global__ __launch_bounds__(256) void order_kernel(
    const int* __restrict__ cnt, int* __restrict__ dcur,
    const float* __restrict__ pos, float* __restrict__ rden,
    int* __restrict__ nodeOrd, float4* __restrict__ pos4g) {
  __shared__ int lh[64];
  __shared__ int lbase[64];
  int t = threadIdx.x, n = blockIdx.x * 256 + t;
  if (t < 64) lh[t] = 0;
  __syncthreads();
  int bin = 0, lrank = 0;
  bool act = (n < NN);
  if (act) {
    int c = cnt[n];
    bin = 63 - (c > 63 ? 63 : c);
    rden[n] = 1.0f / fmaxf((float)c, 1.0f);
    pos4g[n] = make_float4(pos[3 * n], pos[3 * n + 1], pos[3 * n + 2], 0.f);
    lrank = atomicAdd(&lh[bin], 1);
  }
  __syncthreads();
  if (t < 64) lbase[t] = (lh[t] > 0) ? atomicAdd(&dcur[t], lh[t]) : 0;
  __syncthreads();
  if (act) nodeOrd[lbase[bin] + lrank] = n;
}

// ---------------- standalone P13/P2 GEMM (step 0): K=128 + epilogue pos@W3 fold --
__global__ __launch_bounds__(512) void p12_kernel(const short* __restrict__ hb,
                                                  const short* __restrict__ wt12_s,  // [256][128]
                                                  const float4* __restrict__ pos4g,
                                                  const float* __restrict__ w3,  // [3][128]
                                                  short* __restrict__ P12b) {
  __shared__ short wlds[256 * 132];  // 67.6 KB
  __shared__ float w3lds[384];       // 1.5 KB
  const int t = threadIdx.x;
  const int wid = t >> 6, lane = t & 63;
  const int m = lane & 15, kg = lane >> 4;
  for (int i = t * 8; i < 256 * DIM; i += 512 * 8) {
    int r = i >> 7, c = i & 127;
    *(bf16x8*)(&wlds[r * 132 + c]) = *(const bf16x8*)(wt12_s + i);
  }
  if (t < 384) w3lds[t] = w3[t];
  __syncthreads();
  const int wgid = blockIdx.x * 8 + wid;
#pragma unroll
  for (int rep = 0; rep < 2; ++rep) {
    int tid = wgid + rep * 2048;
    if (tid >= NTILE) break;
    int nbase = tid * 16;
    const short* hrow = hb + (size_t)(nbase + m) * DIM;
    const float4 pp = pos4g[nbase + m];
    bf16x8 bfrag[4];
#pragma unroll
    for (int cc = 0; cc < 4; ++cc)
      bfrag[cc] = *(const bf16x8*)(hrow + cc * 32 + kg * 8);
#pragma unroll
    for (int half = 0; half < 2; ++half) {
      f32x4 acc[8];
#pragma unroll
      for (int i = 0; i < 8; ++i) acc[i] = (f32x4)0.0f;
#pragma unroll
      for (int cc = 0; cc < 4; ++cc) {
#pragma unroll
        for (int tl = 0; tl < 8; ++tl) {
          bf16x8 afrag = *(const bf16x8*)(&wlds[(half * DIM + tl * 16 + m) * 132 + cc * 32 + kg * 8]);
          acc[tl] = __builtin_amdgcn_mfma_f32_16x16x32_bf16(afrag, bfrag[cc], acc[tl], 0, 0, 0);
        }
      }
#pragma unroll
      for (int tl = 0; tl < 8; ++tl) {
        bf16x4 p;
#pragma unroll
        for (int j = 0; j < 4; ++j) {
          float val = acc[tl][j];
          if (half == 0) {
            int o = tl * 16 + kg * 4 + j;
            val += pp.x * w3lds[o] + pp.y * w3lds[128 + o] + pp.z * w3lds[256 + o];
          }
          p[j] = f2bf(val);
        }
        *(bf16x4*)(P12b + (size_t)(nbase + m) * 256 + half * DIM + tl * 16 + kg * 4) = p;
      }
    }
  }
}

// ---------------- message + aggregate (fixed-stride buckets) ----------------
__global__ __launch_bounds__(256) void msg_agg_kernel(
    const short* __restrict__ P12b,
    const float4* __restrict__ pos4g,
    const int* __restrict__ rowOf2, const int* __restrict__ cnt,
    const int* __restrict__ nodeOrd, const float* __restrict__ rden,
    const float* __restrict__ wmsg_s,  // msg_w + s*259*128 (f32)
    const float* __restrict__ bias_s, short* __restrict__ aggb) {
  const int t = threadIdx.x;
  const int wid = t >> 6, lane = t & 63;
  const int n = nodeOrd[blockIdx.x * 4 + wid];
  const int q = lane >> 4;
  const int d0 = (lane & 15) * 8;
  f32x2 pbv[4];
  {
    const float4 pc = pos4g[n];
    const float* w30p = wmsg_s + 256 * DIM + d0;
    const float* w31p = wmsg_s + 257 * DIM + d0;
    const float* w32p = wmsg_s + 258 * DIM + d0;
    bf16x8 p2v = *(const bf16x8*)(P12b + (size_t)n * 256 + DIM + d0);
#pragma unroll
    for (int p = 0; p < 4; ++p) {
      f32x2 w0 = *(const f32x2*)(w30p + 2 * p);
      f32x2 w1 = *(const f32x2*)(w31p + 2 * p);
      f32x2 w2 = *(const f32x2*)(w32p + 2 * p);
      f32x2 bb = *(const f32x2*)(bias_s + d0 + 2 * p);
      pbv[p].x = bf2f((unsigned short)p2v[2 * p]) + bb.x
                 - (pc.x * w0.x + pc.y * w1.x + pc.z * w2.x);
      pbv[p].y = bf2f((unsigned short)p2v[2 * p + 1]) + bb.y
                 - (pc.x * w0.y + pc.y * w1.y + pc.z * w2.y);
    }
  }
  int c = cnt[n]; if (c > 64) c = 64;
  const int start = n * 64;
  const int end = start + c;
  f32x2 av[4];
#pragma unroll
  for (int p = 0; p < 4; ++p) av[p] = (f32x2)0.0f;
  float bacc = 0.f;
  const f32x2 gc1 = (f32x2)(-0.102951604f);
  const f32x2 gc0 = (f32x2)(-2.30234934f);
  const f32x2 onev = (f32x2)1.0f;
  if (start < end) {
    const int last = end - 1;
    int ia = start + q; if (ia > last) ia = last;
    int ra = rowOf2[ia];
    bf16x8 p1a = *(const bf16x8*)(P12b + (size_t)ra * 256 + d0);
    int ib = start + 4 + q; if (ib > last) ib = last;
    int rb = rowOf2[ib];
    bf16x8 p1b = *(const bf16x8*)(P12b + (size_t)rb * 256 + d0);
#pragma unroll 2
    for (int jg = start; jg < end; jg += 4) {
      int ic = jg + 8 + q; if (ic > last) ic = last;
      int rc = rowOf2[ic];
      bf16x8 p1c = *(const bf16x8*)(P12b + (size_t)rc * 256 + d0);
      f32x2 g[4];
      f32x2 s1v = (f32x2)0.0f, s2v = (f32x2)0.0f;
#pragma unroll
      for (int p = 0; p < 4; ++p) {
        unsigned int u = ((const unsigned int*)&p1a)[p];
        f32x2 v;
        v.x = __uint_as_float(u << 16);
        v.y = __uint_as_float(u & 0xffff0000u);
        v = v + pbv[p];
        f32x2 u2 = v * v;
        f32x2 wv = __builtin_elementwise_fma(u2, gc1, gc0);
        f32x2 zv = v * wv;
        f32x2 tv;
        tv.x = fexp2(zv.x);
        tv.y = fexp2(zv.y);
        tv = tv + onev;
        f32x2 rv;
        rv.x = frcp(tv.x);
        rv.y = frcp(tv.y);
        f32x2 gg = v * rv;
        g[p] = gg;
        s1v = s1v + gg;
        s2v = __builtin_elementwise_fma(gg, gg, s2v);
      }
      float s1 = s1v.x + s1v.y;
      float s2 = s2v.x + s2v.y;
      s1 = qsum16(s1);
      s2 = qsum16(s2);
      float mean = s1 * (1.0f / 128.0f);
      float tvv = fmaf(mean, -mean, 1e-5f);
      float var = fmaf(s2, 1.0f / 128.0f, tvv);
      float rstd = rsqrtf(var);
      float rs = (jg + q < end) ? rstd : 0.0f;
      bacc = fmaf(mean, rs, bacc);
      f32x2 rsv = (f32x2)rs;
#pragma unroll
      for (int p = 0; p < 4; ++p) av[p] = __builtin_elementwise_fma(g[p], rsv, av[p]);
      p1a = p1b;
      p1b = p1c;
    }
  }
  const float rd = rden[n];
  float out[8];
#pragma unroll
  for (int p = 0; p < 4; ++p) {
    out[2 * p] = av[p].x - bacc;
    out[2 * p + 1] = av[p].y - bacc;
  }
  bf16x8 ob;
#pragma unroll
  for (int k = 0; k < 8; ++k) {
    out[k] += __shfl_xor(out[k], 16, 64);
    out[k] += __shfl_xor(out[k], 32, 64);
    ob[k] = f2bf(out[k] * rd);
  }
  if (q == 0)
    *(bf16x8*)(aggb + (size_t)n * DIM + d0) = ob;
}

// ---------------- fused update + next-step P13/P2 ----------------
template <int FINAL>
__global__ __launch_bounds__(512) void updp12_kernel(
    const short* hb, const short* __restrict__ aggb,
    const short* __restrict__ wtu_s,   // [128][256]
    const short* __restrict__ wt12_n,  // [256][128] for next step
    const float4* __restrict__ pos4g,
    const float* __restrict__ w3_n,    // [3][128] next step
    const float* __restrict__ bias, float* __restrict__ h, short* hbo,
    short* __restrict__ P12b) {
  __shared__ short wlds[33792];  // 67.6 KB; viewed [128][264] then [256][132]
  __shared__ float w3lds[384];   // 1.5 KB
  const int t = threadIdx.x;
  const int wid = t >> 6, lane = t & 63;
  const int m = lane & 15, kg = lane >> 4;
  for (int i = t * 8; i < DIM * 256; i += 512 * 8) {
    int r = i >> 8, c = i & 255;
    *(bf16x8*)(&wlds[r * 264 + c]) = *(const bf16x8*)(wtu_s + i);
  }
  if (!FINAL && t < 384) w3lds[t] = w3_n[t];
  __syncthreads();
  const int wgid = blockIdx.x * 8 + wid;
#pragma unroll
  for (int rep = 0; rep < 2; ++rep) {
    int tid = wgid + rep * 2048;
    if (tid >= NTILE) break;
    int nbase = tid * 16;
    const int nA = nbase + m;
    const short* hrow = hb + (size_t)nA * DIM;
    const short* arow = aggb + (size_t)nA * DIM;

    f32x4 acc[8];
#pragma unroll
    for (int i = 0; i < 8; ++i) acc[i] = (f32x4)0.0f;
#pragma unroll
    for (int cc = 0; cc < 8; ++cc) {
      bf16x8 a = (cc < 4) ? *(const bf16x8*)(hrow + cc * 32 + kg * 8)
                          : *(const bf16x8*)(arow + (cc - 4) * 32 + kg * 8);
#pragma unroll
      for (int tl = 0; tl < 8; ++tl) {
        bf16x8 bfr = *(const bf16x8*)(&wlds[(tl * 16 + m) * 264 + cc * 32 + kg * 8]);
        acc[tl] = __builtin_amdgcn_mfma_f32_16x16x32_bf16(a, bfr, acc[tl], 0, 0, 0);
      }
    }

    float s1[4] = {0.f, 0.f, 0.f, 0.f}, s2[4] = {0.f, 0.f, 0.f, 0.f};
#pragma unroll
    for (int tl = 0; tl < 8; ++tl) {
      float bd = bias[tl * 16 + m];
#pragma unroll
      for (int j = 0; j < 4; ++j) {
        float xv = acc[tl][j] + bd;
        acc[tl][j] = xv;
        s1[j] += xv;
        s2[j] = fmaf(xv, xv, s2[j]);
      }
    }
#pragma unroll
    for (int mask = 1; mask < 16; mask <<= 1) {
#pragma unroll
      for (int j = 0; j < 4; ++j) {
        s1[j] += __shfl_xor(s1[j], mask, 64);
        s2[j] += __shfl_xor(s2[j], mask, 64);
      }
    }
#pragma unroll
    for (int j = 0; j < 4; ++j) {
      float mean = s1[j] * (1.0f / 128.0f);
      float var = s2[j] * (1.0f / 128.0f) - mean * mean;
      float rstd = rsqrtf(var + 1e-5f);
      int nw = nbase + kg * 4 + j;
#pragma unroll
      for (int tl = 0; tl < 8; ++tl) {
        int d = tl * 16 + m;
        float res = bf2f((unsigned short)hb[(size_t)nw * DIM + d]);
        float hv = res + (acc[tl][j] - mean) * rstd;
        if (FINAL) h[(size_t)nw * DIM + d] = hv;
        else       hbo[(size_t)nw * DIM + d] = f2bf(hv);
      }
    }
  }
  if (FINAL) return;

  // ---- phase 2: next-step P13/P2 from freshly written hbo ----
  __syncthreads();
  for (int i = t * 8; i < 256 * DIM; i += 512 * 8) {
    int r = i >> 7, c = i & 127;
    *(bf16x8*)(&wlds[r * 132 + c]) = *(const bf16x8*)(wt12_n + i);
  }
  __syncthreads();
#pragma unroll
  for (int rep = 0; rep < 2; ++rep) {
    int tid = wgid + rep * 2048;
    if (tid >= NTILE) break;
    int nbase = tid * 16;
    const short* hrow = hbo + (size_t)(nbase + m) * DIM;
    const float4 pp = pos4g[nbase + m];
    bf16x8 bfrag[4];
#pragma unroll
    for (int cc = 0; cc < 4; ++cc)
      bfrag[cc] = *(const bf16x8*)(hrow + cc * 32 + kg * 8);
#pragma unroll
    for (int half = 0; half < 2; ++half) {
      f32x4 acc[8];
#pragma unroll
      for (int i = 0; i < 8; ++i) acc[i] = (f32x4)0.0f;
#pragma unroll
      for (int cc = 0; cc < 4; ++cc) {
#pragma unroll
        for (int tl = 0; tl < 8; ++tl) {
          bf16x8 afrag = *(const bf16x8*)(&wlds[(half * DIM + tl * 16 + m) * 132 + cc * 32 + kg * 8]);
          acc[tl] = __builtin_amdgcn_mfma_f32_16x16x32_bf16(afrag, bfrag[cc], acc[tl], 0, 0, 0);
        }
      }
#pragma unroll
      for (int tl = 0; tl < 8; ++tl) {
        bf16x4 p;
#pragma unroll
        for (int j = 0; j < 4; ++j) {
          float val = acc[tl][j];
          if (half == 0) {
            int o = tl * 16 + kg * 4 + j;
            val += pp.x * w3lds[o] + pp.y * w3lds[128 + o] + pp.z * w3lds[256 + o];
          }
          p[j] = f2bf(val);
        }
        *(bf16x4*)(P12b + (size_t)(nbase + m) * 256 + half * DIM + tl * 16 + kg * 4) = p;
      }
    }
  }
}

extern "C" void kernel_launch(void* const* d_in, const int* in_sizes, int n_in,
                              void* d_out, int out_size, void* d_ws, size_t ws_size,
                              hipStream_t stream) {
  const float* x       = (const float*)d_in[0];
  const float* pos     = (const float*)d_in[1];
  const int* ei        = (const int*)d_in[2];
  const float* embed_w = (const float*)d_in[3];
  const float* embed_b = (const float*)d_in[4];
  const float* msg_w   = (const float*)d_in[5];
  const float* msg_b   = (const float*)d_in[6];
  const float* upd_w   = (const float*)d_in[7];
  const float* upd_b   = (const float*)d_in[8];
  float* h = (float*)d_out;

  char* ws = (char*)d_ws;
  size_t off_b = 0;
  short* hb     = (short*)(ws + off_b);  off_b += (size_t)NN * DIM * 2;
  short* P12b   = (short*)(ws + off_b);  off_b += (size_t)NN * 256 * 2;
  short* aggb   = (short*)(ws + off_b);  off_b += (size_t)NN * DIM * 2;
  float* rden   = (float*)(ws + off_b);  off_b += (size_t)NN * 4;
  int*   cnt    = (int*)(ws + off_b);    off_b += (size_t)NN * 4;
  int*   rowOf2 = (int*)(ws + off_b);    off_b += (size_t)NN * 64 * 4;   // 12.8 MB
  int*   dhist  = (int*)(ws + off_b);    off_b += (size_t)64 * 4;
  int*   dcur   = (int*)(ws + off_b);    off_b += (size_t)64 * 4;
  int*   nodeOrd= (int*)(ws + off_b);    off_b += (size_t)NN * 4;
  float4* pos4g = (float4*)(ws + off_b); off_b += (size_t)NN * 16;
  short* wt12   = (short*)(ws + off_b);  off_b += (size_t)3 * 256 * DIM * 2;
  short* wtu    = (short*)(ws + off_b);  off_b += (size_t)3 * DIM * KUPD * 2;

  hipMemsetAsync(cnt, 0, (size_t)NN * 4, stream);
  hipMemsetAsync(dhist, 0, 64 * 4, stream);
  scatter_wt_kernel<<<NB_SCT1 + NB_WT, 256, 0, stream>>>(ei, cnt, rowOf2,
                                                         msg_w, upd_w, wt12, wtu);
  embed_kernel<<<NN / 8, 256, 0, stream>>>(x, embed_w, embed_b, hb);
  dhist_kernel<<<NB_SCAN, 256, 0, stream>>>(cnt, dhist);
  dscan_kernel<<<1, 64, 0, stream>>>(dhist, dcur);
  order_kernel<<<NB_SCAN, 256, 0, stream>>>(cnt, dcur, pos, rden, nodeOrd, pos4g);
  p12_kernel<<<256, 512, 0, stream>>>(hb, wt12, pos4g, msg_w + 256 * DIM, P12b);

  for (int s = 0; s < 3; ++s) {
    msg_agg_kernel<<<NN / 4, 256, 0, stream>>>(P12b, pos4g, rowOf2, cnt, nodeOrd, rden,
                                               msg_w + (size_t)s * 259 * DIM,
                                               msg_b + (size_t)s * DIM, aggb);
    if (s < 2)
      updp12_kernel<0><<<256, 512, 0, stream>>>(
          hb, aggb, wtu + (size_t)s * DIM * KUPD,
          wt12 + (size_t)(s + 1) * 256 * DIM, pos4g,
          msg_w + (size_t)(s + 1) * 259 * DIM + 256 * DIM,
          upd_b + (size_t)s * DIM, h, hb, P12b);
    else
      updp12_kernel<1><<<256, 512, 0, stream>>>(
          hb, aggb, wtu + (size_t)s * DIM * KUPD,
          wt12, pos4g, msg_w,
          upd_b + (size_t)s * DIM, h, hb, P12b);
  }
}

// Round 17
// 336.914 us; speedup vs baseline: 1.3699x; 1.0363x over previous
//
#include <hip/hip_runtime.h>
#include <hip/hip_bf16.h>

#define NN 50000
#define NE 800000
#define IND 64
#define DIM 128
#define KUPD 256
#define NB_SCAN 196  // ceil(NN/256)
#define NTILE 3125   // NN/16
#define NB_SCT1 3125 // NE/256
#define NB_WT 768

typedef __attribute__((ext_vector_type(8))) short bf16x8;
typedef __attribute__((ext_vector_type(4))) short bf16x4;
typedef __attribute__((ext_vector_type(4))) float f32x4;
typedef __attribute__((ext_vector_type(2))) float f32x2;

static __device__ __forceinline__ short f2bf(float f) {
  union { __hip_bfloat16 b; short s; } u;
  u.b = __float2bfloat16(f);
  return u.s;
}
static __device__ __forceinline__ float bf2f(unsigned short u) {
  union { float f; unsigned int i; } x; x.i = ((unsigned int)u) << 16; return x.f;
}
static __device__ __forceinline__ float fexp2(float x) {
  float r; asm("v_exp_f32 %0, %1" : "=v"(r) : "v"(x)); return r;
}
static __device__ __forceinline__ float frcp(float x) {
  float r; asm("v_rcp_f32 %0, %1" : "=v"(r) : "v"(x)); return r;
}
// sum across the 16-lane quarter via DPP row rotates (row = 16 lanes on CDNA)
static __device__ __forceinline__ float qsum16(float x) {
  x += __int_as_float(__builtin_amdgcn_mov_dpp(__float_as_int(x), 0x128, 0xf, 0xf, false));
  x += __int_as_float(__builtin_amdgcn_mov_dpp(__float_as_int(x), 0x124, 0xf, 0xf, false));
  x += __int_as_float(__builtin_amdgcn_mov_dpp(__float_as_int(x), 0x122, 0xf, 0xf, false));
  x += __int_as_float(__builtin_amdgcn_mov_dpp(__float_as_int(x), 0x121, 0xf, 0xf, false));
  return x;
}

// ---------------- embed: hb = bf16(x @ W + b) ----------------
__global__ __launch_bounds__(256) void embed_kernel(
    const float* __restrict__ x, const float* __restrict__ w,
    const float* __restrict__ b, short* __restrict__ hb) {
  __shared__ float ws[IND * DIM];
  __shared__ float xs[8 * IND];
  const int t = threadIdx.x;
  for (int i = t * 4; i < IND * DIM; i += 1024)
    *(float4*)(ws + i) = *(const float4*)(w + i);
  {
    int i = t * 4;
    if (i < 8 * IND)
      *(float4*)(xs + i) = *(const float4*)(x + (size_t)blockIdx.x * (8 * IND) + i);
  }
  __syncthreads();
  const int d = t & 127, g = t >> 7;
  const float bd = b[d];
  for (int nnod = g; nnod < 8; nnod += 2) {
    float acc = bd;
#pragma unroll
    for (int k = 0; k < IND; ++k) acc += xs[nnod * IND + k] * ws[k * DIM + d];
    const size_t n = (size_t)blockIdx.x * 8 + nnod;
    hb[n * DIM + d] = f2bf(acc);
  }
}

// ---- single-pass edge bucketing (cnt + rowOf2) fused with weight transposes ----
__global__ __launch_bounds__(256) void scatter_wt_kernel(
    const int* __restrict__ ei, int* __restrict__ cnt, int* __restrict__ rowOf2,
    const float* __restrict__ wm, const float* __restrict__ wu,
    short* __restrict__ wt12, short* __restrict__ wtu) {
  const int bid = blockIdx.x, t = threadIdx.x;
  if (bid < NB_SCT1) {
    int e = bid * 256 + t;
    if (e < NE) {
      int c = ei[NE + e];
      int r = atomicAdd(&cnt[c], 1);
      if (r < 64) rowOf2[(size_t)c * 64 + r] = ei[e];
    }
  } else {
    int i = (bid - NB_SCT1) * 256 + t;
    if (i < 3 * 256 * DIM) {
      int k = i % DIM, o = (i / DIM) % 256, s = i / (DIM * 256);
      int krow = (o < DIM) ? k : (DIM + k);
      int d = o & (DIM - 1);
      wt12[i] = f2bf(wm[((size_t)s * 259 + krow) * DIM + d]);
    } else {
      int j = i - 3 * 256 * DIM;
      if (j < 3 * DIM * KUPD) {
        int k = j % KUPD, d = (j / KUPD) % DIM, s = j / (KUPD * DIM);
        wtu[j] = f2bf(wu[((size_t)s * KUPD + k) * DIM + d]);
      }
    }
  }
}

// ---------------- degree histogram (LDS-aggregated) ----------------
__global__ __launch_bounds__(256) void dhist_kernel(const int* __restrict__ cnt,
                                                    int* __restrict__ dhist) {
  __shared__ int lh[64];
  int t = threadIdx.x, n = blockIdx.x * 256 + t;
  if (t < 64) lh[t] = 0;
  __syncthreads();
  if (n < NN) {
    int d = cnt[n]; if (d > 63) d = 63;
    atomicAdd(&lh[63 - d], 1);
  }
  __syncthreads();
  if (t < 64 && lh[t] > 0) atomicAdd(&dhist[t], lh[t]);
}

// ---------------- order + rden + pos4 (in-kernel 64-bin scan of dhist) ----------
__global__ __launch_bounds__(256) void order_kernel(
    const int* __restrict__ cnt, const int* __restrict__ dhist,
    int* __restrict__ dcur2,
    const float* __restrict__ pos, float* __restrict__ rden,
    int* __restrict__ nodeOrd, float4* __restrict__ pos4g) {
  __shared__ int lh[64];
  __shared__ int sbase[64];
  __shared__ int lbase[64];
  int t = threadIdx.x, n = blockIdx.x * 256 + t;
  if (t < 64) {
    lh[t] = 0;
    int v = dhist[t];
    int s = v;
    for (int d = 1; d < 64; d <<= 1) {
      int u = __shfl_up(s, d, 64);
      if (t >= d) s += u;
    }
    sbase[t] = s - v;  // exclusive scan of dhist
  }
  __syncthreads();
  int bin = 0, lrank = 0;
  bool act = (n < NN);
  if (act) {
    int c = cnt[n];
    bin = 63 - (c > 63 ? 63 : c);
    rden[n] = 1.0f / fmaxf((float)c, 1.0f);
    pos4g[n] = make_float4(pos[3 * n], pos[3 * n + 1], pos[3 * n + 2], 0.f);
    lrank = atomicAdd(&lh[bin], 1);
  }
  __syncthreads();
  if (t < 64) lbase[t] = (lh[t] > 0) ? (sbase[t] + atomicAdd(&dcur2[t], lh[t])) : 0;
  __syncthreads();
  if (act) nodeOrd[lbase[bin] + lrank] = n;
}

// ---------------- standalone P13/P2 GEMM (step 0): K=128 + epilogue pos@W3 fold --
__global__ __launch_bounds__(512) void p12_kernel(const short* __restrict__ hb,
                                                  const short* __restrict__ wt12_s,  // [256][128]
                                                  const float4* __restrict__ pos4g,
                                                  const float* __restrict__ w3,  // [3][128]
                                                  short* __restrict__ P12b) {
  __shared__ short wlds[256 * 132];  // 67.6 KB
  __shared__ float w3lds[384];       // 1.5 KB
  const int t = threadIdx.x;
  const int wid = t >> 6, lane = t & 63;
  const int m = lane & 15, kg = lane >> 4;
  for (int i = t * 8; i < 256 * DIM; i += 512 * 8) {
    int r = i >> 7, c = i & 127;
    *(bf16x8*)(&wlds[r * 132 + c]) = *(const bf16x8*)(wt12_s + i);
  }
  if (t < 384) w3lds[t] = w3[t];
  __syncthreads();
  const int wgid = blockIdx.x * 8 + wid;
#pragma unroll
  for (int rep = 0; rep < 2; ++rep) {
    int tid = wgid + rep * 2048;
    if (tid >= NTILE) break;
    int nbase = tid * 16;
    const short* hrow = hb + (size_t)(nbase + m) * DIM;
    const float4 pp = pos4g[nbase + m];
    bf16x8 bfrag[4];
#pragma unroll
    for (int cc = 0; cc < 4; ++cc)
      bfrag[cc] = *(const bf16x8*)(hrow + cc * 32 + kg * 8);
#pragma unroll
    for (int half = 0; half < 2; ++half) {
      f32x4 acc[8];
#pragma unroll
      for (int i = 0; i < 8; ++i) acc[i] = (f32x4)0.0f;
#pragma unroll
      for (int cc = 0; cc < 4; ++cc) {
#pragma unroll
        for (int tl = 0; tl < 8; ++tl) {
          bf16x8 afrag = *(const bf16x8*)(&wlds[(half * DIM + tl * 16 + m) * 132 + cc * 32 + kg * 8]);
          acc[tl] = __builtin_amdgcn_mfma_f32_16x16x32_bf16(afrag, bfrag[cc], acc[tl], 0, 0, 0);
        }
      }
#pragma unroll
      for (int tl = 0; tl < 8; ++tl) {
        bf16x4 p;
#pragma unroll
        for (int j = 0; j < 4; ++j) {
          float val = acc[tl][j];
          if (half == 0) {
            int o = tl * 16 + kg * 4 + j;
            val += pp.x * w3lds[o] + pp.y * w3lds[128 + o] + pp.z * w3lds[256 + o];
          }
          p[j] = f2bf(val);
        }
        *(bf16x4*)(P12b + (size_t)(nbase + m) * 256 + half * DIM + tl * 16 + kg * 4) = p;
      }
    }
  }
}

// ---------------- message + aggregate (fixed-stride buckets; sigmoid-1.702 gelu) --
__global__ __launch_bounds__(256) void msg_agg_kernel(
    const short* __restrict__ P12b,
    const float4* __restrict__ pos4g,
    const int* __restrict__ rowOf2, const int* __restrict__ cnt,
    const int* __restrict__ nodeOrd, const float* __restrict__ rden,
    const float* __restrict__ wmsg_s,  // msg_w + s*259*128 (f32)
    const float* __restrict__ bias_s, short* __restrict__ aggb) {
  const int t = threadIdx.x;
  const int wid = t >> 6, lane = t & 63;
  const int n = nodeOrd[blockIdx.x * 4 + wid];
  const int q = lane >> 4;
  const int d0 = (lane & 15) * 8;
  f32x2 pbv[4];
  {
    const float4 pc = pos4g[n];
    const float* w30p = wmsg_s + 256 * DIM + d0;
    const float* w31p = wmsg_s + 257 * DIM + d0;
    const float* w32p = wmsg_s + 258 * DIM + d0;
    bf16x8 p2v = *(const bf16x8*)(P12b + (size_t)n * 256 + DIM + d0);
#pragma unroll
    for (int p = 0; p < 4; ++p) {
      f32x2 w0 = *(const f32x2*)(w30p + 2 * p);
      f32x2 w1 = *(const f32x2*)(w31p + 2 * p);
      f32x2 w2 = *(const f32x2*)(w32p + 2 * p);
      f32x2 bb = *(const f32x2*)(bias_s + d0 + 2 * p);
      pbv[p].x = bf2f((unsigned short)p2v[2 * p]) + bb.x
                 - (pc.x * w0.x + pc.y * w1.x + pc.z * w2.x);
      pbv[p].y = bf2f((unsigned short)p2v[2 * p + 1]) + bb.y
                 - (pc.x * w0.y + pc.y * w1.y + pc.z * w2.y);
    }
  }
  int c = cnt[n]; if (c > 64) c = 64;
  const int start = n * 64;
  const int end = start + c;
  f32x2 av[4];
#pragma unroll
  for (int p = 0; p < 4; ++p) av[p] = (f32x2)0.0f;
  float bacc = 0.f;
  const f32x2 gcs = (f32x2)(-2.45556851f);  // -1.702 * log2(e)
  const f32x2 onev = (f32x2)1.0f;
  if (start < end) {
    const int last = end - 1;
    int ia = start + q; if (ia > last) ia = last;
    int ra = rowOf2[ia];
    bf16x8 p1a = *(const bf16x8*)(P12b + (size_t)ra * 256 + d0);
    int ib = start + 4 + q; if (ib > last) ib = last;
    int rb = rowOf2[ib];
    bf16x8 p1b = *(const bf16x8*)(P12b + (size_t)rb * 256 + d0);
#pragma unroll 2
    for (int jg = start; jg < end; jg += 4) {
      int ic = jg + 8 + q; if (ic > last) ic = last;
      int rc = rowOf2[ic];
      bf16x8 p1c = *(const bf16x8*)(P12b + (size_t)rc * 256 + d0);
      f32x2 g[4];
      f32x2 s1v = (f32x2)0.0f, s2v = (f32x2)0.0f;
#pragma unroll
      for (int p = 0; p < 4; ++p) {
        unsigned int u = ((const unsigned int*)&p1a)[p];
        f32x2 v;
        v.x = __uint_as_float(u << 16);
        v.y = __uint_as_float(u & 0xffff0000u);
        v = v + pbv[p];
        f32x2 zv = v * gcs;
        f32x2 tv;
        tv.x = fexp2(zv.x);
        tv.y = fexp2(zv.y);
        tv = tv + onev;
        f32x2 rv;
        rv.x = frcp(tv.x);
        rv.y = frcp(tv.y);
        f32x2 gg = v * rv;
        g[p] = gg;
        s1v = s1v + gg;
        s2v = __builtin_elementwise_fma(gg, gg, s2v);
      }
      float s1 = s1v.x + s1v.y;
      float s2 = s2v.x + s2v.y;
      s1 = qsum16(s1);
      s2 = qsum16(s2);
      float mean = s1 * (1.0f / 128.0f);
      float tvv = fmaf(mean, -mean, 1e-5f);
      float var = fmaf(s2, 1.0f / 128.0f, tvv);
      float rstd = rsqrtf(var);
      float rs = (jg + q < end) ? rstd : 0.0f;
      bacc = fmaf(mean, rs, bacc);
      f32x2 rsv = (f32x2)rs;
#pragma unroll
      for (int p = 0; p < 4; ++p) av[p] = __builtin_elementwise_fma(g[p], rsv, av[p]);
      p1a = p1b;
      p1b = p1c;
    }
  }
  const float rd = rden[n];
  float out[8];
#pragma unroll
  for (int p = 0; p < 4; ++p) {
    out[2 * p] = av[p].x - bacc;
    out[2 * p + 1] = av[p].y - bacc;
  }
  bf16x8 ob;
#pragma unroll
  for (int k = 0; k < 8; ++k) {
    out[k] += __shfl_xor(out[k], 16, 64);
    out[k] += __shfl_xor(out[k], 32, 64);
    ob[k] = f2bf(out[k] * rd);
  }
  if (q == 0)
    *(bf16x8*)(aggb + (size_t)n * DIM + d0) = ob;
}

// ---------------- fused update + next-step P13/P2 ----------------
template <int FINAL>
__global__ __launch_bounds__(512) void updp12_kernel(
    const short* hb, const short* __restrict__ aggb,
    const short* __restrict__ wtu_s,   // [128][256]
    const short* __restrict__ wt12_n,  // [256][128] for next step
    const float4* __restrict__ pos4g,
    const float* __restrict__ w3_n,    // [3][128] next step
    const float* __restrict__ bias, float* __restrict__ h, short* hbo,
    short* __restrict__ P12b) {
  __shared__ short wlds[33792];  // 67.6 KB; viewed [128][264] then [256][132]
  __shared__ float w3lds[384];   // 1.5 KB
  const int t = threadIdx.x;
  const int wid = t >> 6, lane = t & 63;
  const int m = lane & 15, kg = lane >> 4;
  for (int i = t * 8; i < DIM * 256; i += 512 * 8) {
    int r = i >> 8, c = i & 255;
    *(bf16x8*)(&wlds[r * 264 + c]) = *(const bf16x8*)(wtu_s + i);
  }
  if (!FINAL && t < 384) w3lds[t] = w3_n[t];
  __syncthreads();
  const int wgid = blockIdx.x * 8 + wid;
#pragma unroll
  for (int rep = 0; rep < 2; ++rep) {
    int tid = wgid + rep * 2048;
    if (tid >= NTILE) break;
    int nbase = tid * 16;
    const int nA = nbase + m;
    const short* hrow = hb + (size_t)nA * DIM;
    const short* arow = aggb + (size_t)nA * DIM;

    f32x4 acc[8];
#pragma unroll
    for (int i = 0; i < 8; ++i) acc[i] = (f32x4)0.0f;
#pragma unroll
    for (int cc = 0; cc < 8; ++cc) {
      bf16x8 a = (cc < 4) ? *(const bf16x8*)(hrow + cc * 32 + kg * 8)
                          : *(const bf16x8*)(arow + (cc - 4) * 32 + kg * 8);
#pragma unroll
      for (int tl = 0; tl < 8; ++tl) {
        bf16x8 bfr = *(const bf16x8*)(&wlds[(tl * 16 + m) * 264 + cc * 32 + kg * 8]);
        acc[tl] = __builtin_amdgcn_mfma_f32_16x16x32_bf16(a, bfr, acc[tl], 0, 0, 0);
      }
    }

    float s1[4] = {0.f, 0.f, 0.f, 0.f}, s2[4] = {0.f, 0.f, 0.f, 0.f};
#pragma unroll
    for (int tl = 0; tl < 8; ++tl) {
      float bd = bias[tl * 16 + m];
#pragma unroll
      for (int j = 0; j < 4; ++j) {
        float xv = acc[tl][j] + bd;
        acc[tl][j] = xv;
        s1[j] += xv;
        s2[j] = fmaf(xv, xv, s2[j]);
      }
    }
#pragma unroll
    for (int mask = 1; mask < 16; mask <<= 1) {
#pragma unroll
      for (int j = 0; j < 4; ++j) {
        s1[j] += __shfl_xor(s1[j], mask, 64);
        s2[j] += __shfl_xor(s2[j], mask, 64);
      }
    }
#pragma unroll
    for (int j = 0; j < 4; ++j) {
      float mean = s1[j] * (1.0f / 128.0f);
      float var = s2[j] * (1.0f / 128.0f) - mean * mean;
      float rstd = rsqrtf(var + 1e-5f);
      int nw = nbase + kg * 4 + j;
#pragma unroll
      for (int tl = 0; tl < 8; ++tl) {
        int d = tl * 16 + m;
        float res = bf2f((unsigned short)hb[(size_t)nw * DIM + d]);
        float hv = res + (acc[tl][j] - mean) * rstd;
        if (FINAL) h[(size_t)nw * DIM + d] = hv;
        else       hbo[(size_t)nw * DIM + d] = f2bf(hv);
      }
    }
  }
  if (FINAL) return;

  // ---- phase 2: next-step P13/P2 from freshly written hbo ----
  __syncthreads();
  for (int i = t * 8; i < 256 * DIM; i += 512 * 8) {
    int r = i >> 7, c = i & 127;
    *(bf16x8*)(&wlds[r * 132 + c]) = *(const bf16x8*)(wt12_n + i);
  }
  __syncthreads();
#pragma unroll
  for (int rep = 0; rep < 2; ++rep) {
    int tid = wgid + rep * 2048;
    if (tid >= NTILE) break;
    int nbase = tid * 16;
    const short* hrow = hbo + (size_t)(nbase + m) * DIM;
    const float4 pp = pos4g[nbase + m];
    bf16x8 bfrag[4];
#pragma unroll
    for (int cc = 0; cc < 4; ++cc)
      bfrag[cc] = *(const bf16x8*)(hrow + cc * 32 + kg * 8);
#pragma unroll
    for (int half = 0; half < 2; ++half) {
      f32x4 acc[8];
#pragma unroll
      for (int i = 0; i < 8; ++i) acc[i] = (f32x4)0.0f;
#pragma unroll
      for (int cc = 0; cc < 4; ++cc) {
#pragma unroll
        for (int tl = 0; tl < 8; ++tl) {
          bf16x8 afrag = *(const bf16x8*)(&wlds[(half * DIM + tl * 16 + m) * 132 + cc * 32 + kg * 8]);
          acc[tl] = __builtin_amdgcn_mfma_f32_16x16x32_bf16(afrag, bfrag[cc], acc[tl], 0, 0, 0);
        }
      }
#pragma unroll
      for (int tl = 0; tl < 8; ++tl) {
        bf16x4 p;
#pragma unroll
        for (int j = 0; j < 4; ++j) {
          float val = acc[tl][j];
          if (half == 0) {
            int o = tl * 16 + kg * 4 + j;
            val += pp.x * w3lds[o] + pp.y * w3lds[128 + o] + pp.z * w3lds[256 + o];
          }
          p[j] = f2bf(val);
        }
        *(bf16x4*)(P12b + (size_t)(nbase + m) * 256 + half * DIM + tl * 16 + kg * 4) = p;
      }
    }
  }
}

extern "C" void kernel_launch(void* const* d_in, const int* in_sizes, int n_in,
                              void* d_out, int out_size, void* d_ws, size_t ws_size,
                              hipStream_t stream) {
  const float* x       = (const float*)d_in[0];
  const float* pos     = (const float*)d_in[1];
  const int* ei        = (const int*)d_in[2];
  const float* embed_w = (const float*)d_in[3];
  const float* embed_b = (const float*)d_in[4];
  const float* msg_w   = (const float*)d_in[5];
  const float* msg_b   = (const float*)d_in[6];
  const float* upd_w   = (const float*)d_in[7];
  const float* upd_b   = (const float*)d_in[8];
  float* h = (float*)d_out;

  char* ws = (char*)d_ws;
  size_t off_b = 0;
  short* hb     = (short*)(ws + off_b);  off_b += (size_t)NN * DIM * 2;
  short* P12b   = (short*)(ws + off_b);  off_b += (size_t)NN * 256 * 2;
  short* aggb   = (short*)(ws + off_b);  off_b += (size_t)NN * DIM * 2;
  float* rden   = (float*)(ws + off_b);  off_b += (size_t)NN * 4;
  int*   cnt    = (int*)(ws + off_b);    off_b += (size_t)NN * 4;
  int*   rowOf2 = (int*)(ws + off_b);    off_b += (size_t)NN * 64 * 4;   // 12.8 MB
  int*   dhist  = (int*)(ws + off_b);    off_b += (size_t)64 * 4;
  int*   dcur2  = (int*)(ws + off_b);    off_b += (size_t)64 * 4;
  int*   nodeOrd= (int*)(ws + off_b);    off_b += (size_t)NN * 4;
  float4* pos4g = (float4*)(ws + off_b); off_b += (size_t)NN * 16;
  short* wt12   = (short*)(ws + off_b);  off_b += (size_t)3 * 256 * DIM * 2;
  short* wtu    = (short*)(ws + off_b);  off_b += (size_t)3 * DIM * KUPD * 2;

  hipMemsetAsync(cnt, 0, (size_t)NN * 4, stream);
  hipMemsetAsync(dhist, 0, 128 * 4, stream);  // dhist + dcur2 (contiguous)
  scatter_wt_kernel<<<NB_SCT1 + NB_WT, 256, 0, stream>>>(ei, cnt, rowOf2,
                                                         msg_w, upd_w, wt12, wtu);
  embed_kernel<<<NN / 8, 256, 0, stream>>>(x, embed_w, embed_b, hb);
  dhist_kernel<<<NB_SCAN, 256, 0, stream>>>(cnt, dhist);
  order_kernel<<<NB_SCAN, 256, 0, stream>>>(cnt, dhist, dcur2, pos, rden, nodeOrd, pos4g);
  p12_kernel<<<256, 512, 0, stream>>>(hb, wt12, pos4g, msg_w + 256 * DIM, P12b);

  for (int s = 0; s < 3; ++s) {
    msg_agg_kernel<<<NN / 4, 256, 0, stream>>>(P12b, pos4g, rowOf2, cnt, nodeOrd, rden,
                                               msg_w + (size_t)s * 259 * DIM,
                                               msg_b + (size_t)s * DIM, aggb);
    if (s < 2)
      updp12_kernel<0><<<256, 512, 0, stream>>>(
          hb, aggb, wtu + (size_t)s * DIM * KUPD,
          wt12 + (size_t)(s + 1) * 256 * DIM, pos4g,
          msg_w + (size_t)(s + 1) * 259 * DIM + 256 * DIM,
          upd_b + (size_t)s * DIM, h, hb, P12b);
    else
      updp12_kernel<1><<<256, 512, 0, stream>>>(
          hb, aggb, wtu + (size_t)s * DIM * KUPD,
          wt12, pos4g, msg_w,
          upd_b + (size_t)s * DIM, h, hb, P12b);
  }
}